// Round 2
// baseline (767.410 us; speedup 1.0000x reference)
//
#include <hip/hip_runtime.h>
#include <stdint.h>

// ---------------------------------------------------------------------------
// SchNetLayer on MI355X (gfx950).
// I/O dtypes: float tensors are FLOAT32 (per reference), indices int32.
// Internal compute: bf16 MFMA (threshold is bf16-grade: 8*2^-8*max|ref|).
//
// Pipeline (8 stream ops):
//   k_zero : z = 0                                  [8192,768] f32
//   k_prep : cast+transpose h_w, w1[3], w2[3], g[3] -> bf16 ws
//   k_he   : he = bf16(electrons_f32) @ h_w         [8192,256] bf16 out
//   k_mlp1 : midact = SSP(bf16(dist_f32) @ w1 + b1) [3][E,128] bf16 out
//   k_scat : we = midact @ w2; z[recv] += we * src[sender]  (f32 atomics;
//            src = he (bf16, same/anti) or nuclei (f32, n))
//   k_cvt  : zbf = bf16(z)
//   k_final: out = electrons_f32 + zbf @ g_catT     f32 out
// ---------------------------------------------------------------------------

#define N_ELEC 8192
#define N_NUC  512
#define EMB    256
#define KER    256
#define DF     64
#define MID    128
#define NEDGE  131072

using u16 = unsigned short;
typedef short short8 __attribute__((ext_vector_type(8)));
typedef float f32x4 __attribute__((ext_vector_type(4)));

__device__ __forceinline__ float bf2f(u16 h) {
  return __uint_as_float(((unsigned)h) << 16);
}
__device__ __forceinline__ u16 f2bf(float f) {
  unsigned u = __float_as_uint(f);
  return (u16)((u + 0x7FFFu + ((u >> 16) & 1u)) >> 16);  // RNE
}
__device__ __forceinline__ float ssp(float x) {
  // shifted softplus: log(0.5 e^x + 0.5) = softplus(x) - log 2
  float sp = (x > 20.0f) ? x : log1pf(expf(x));
  return sp - 0.69314718055994531f;
}

// Stage a 128x32 bf16 tile (row-major source, row stride in bytes) into an
// 8 KB LDS buffer laid out [128][32] bf16 (64 B rows), via global_load_lds.
// LDS dst semantics: wave-uniform base + lane*16.
__device__ __forceinline__ void stage_tile(const char* g0, long stride,
                                           char* lds, int tid) {
  const int l = tid & 63, w = tid >> 6;
#pragma unroll
  for (int c = 0; c < 2; ++c) {
    const int r = c * 64 + w * 16 + (l >> 2);   // tile row this lane fetches
    const int cb = (l & 3) * 16;                // byte offset within 64 B row
    const char* g = g0 + (long)r * stride + cb;
    char* dst = lds + c * 4096 + w * 1024;      // wave-uniform base
    __builtin_amdgcn_global_load_lds(
        (const __attribute__((address_space(1))) unsigned*)g,
        (__attribute__((address_space(3))) unsigned*)dst, 16, 0, 0);
  }
}

// Stage a 128x32 tile of an f32 row-major matrix (element stride) into the
// same [128][32]-bf16 LDS layout, converting f32->bf16 in VGPRs.
// Coalesced float2 loads; packed u32 LDS writes (2-way bank alias = free).
__device__ __forceinline__ void stage_f32(const float* g0, int stride_e,
                                          int kt, char* lds, int tid) {
#pragma unroll
  for (int k = 0; k < 8; ++k) {
    const int idx2 = k * 256 + tid;       // 2048 float2 slots in the tile
    const int row = idx2 >> 4, cp = idx2 & 15;
    const float2 v = *(const float2*)(g0 + (long)row * stride_e + kt + cp * 2);
    const unsigned p = ((unsigned)f2bf(v.y) << 16) | (unsigned)f2bf(v.x);
    *(unsigned*)(lds + row * 64 + cp * 4) = p;
  }
}

// 128x128 output tile GEMM core: C = A[128,K] * Bt[128,K]^T, bf16 MFMA,
// 4 waves in 2x2 quadrants, each wave 4x4 fragments of 16x16x32.
// A_F32: A comes from an f32 matrix (stage_f32); else bf16 (global_load_lds).
template <bool A_F32>
__device__ __forceinline__ void gemm_core(const char* A0, long as_bytes,
                                          const float* Af, int as_elems,
                                          const char* B0, long bs, int K,
                                          char* As, char* Bs,
                                          f32x4 acc[4][4], int tid) {
  const int l = tid & 63, lane15 = l & 15, quad = l >> 4, wv = tid >> 6;
  const int mw = (wv >> 1) * 64, nw = (wv & 1) * 64;
  for (int kt = 0; kt < K; kt += 32) {
    if (A_F32)
      stage_f32(Af, as_elems, kt, As, tid);
    else
      stage_tile(A0 + (long)kt * 2, as_bytes, As, tid);
    stage_tile(B0 + (long)kt * 2, bs, Bs, tid);
    __syncthreads();  // drains vmcnt+lgkm -> LDS tiles valid
    short8 af[4], bf[4];
#pragma unroll
    for (int i = 0; i < 4; ++i) {
      af[i] = *(const short8*)(As + (mw + i * 16 + lane15) * 64 + quad * 16);
      bf[i] = *(const short8*)(Bs + (nw + i * 16 + lane15) * 64 + quad * 16);
    }
#pragma unroll
    for (int mi = 0; mi < 4; ++mi)
#pragma unroll
      for (int ni = 0; ni < 4; ++ni)
        acc[mi][ni] = __builtin_amdgcn_mfma_f32_16x16x32_bf16(
            af[mi], bf[ni], acc[mi][ni], 0, 0, 0);
    __syncthreads();  // protect LDS before next staging round
  }
}

__device__ __forceinline__ void zero_acc(f32x4 acc[4][4]) {
#pragma unroll
  for (int i = 0; i < 4; ++i)
#pragma unroll
    for (int j = 0; j < 4; ++j) acc[i][j] = (f32x4){0.f, 0.f, 0.f, 0.f};
}

// ------------------------------- z = 0 --------------------------------------
__global__ __launch_bounds__(256) void k_zero(float4* z) {
  z[blockIdx.x * 256 + threadIdx.x] = (float4){0.f, 0.f, 0.f, 0.f};
}

// ------------------ prep: f32 weights -> transposed bf16 --------------------
// hwT [KER][EMB], w1T [3][MID][DF], w2T [3][KER][MID], gT [EMB][3*KER]
__global__ __launch_bounds__(256) void k_prep(
    const float* h_w, const float* w1s, const float* w1a, const float* w1n,
    const float* w2s, const float* w2a, const float* w2n,
    const float* gs, const float* ga, const float* gn,
    u16* hwT, u16* w1T, u16* w2T, u16* gT) {
  int i = blockIdx.x * 256 + threadIdx.x;
  if (i < 65536) {  // hwT[n][k] = h_w[k][n]
    int n = i >> 8, k = i & 255;
    hwT[i] = f2bf(h_w[k * 256 + n]);
    return;
  }
  int j = i - 65536;
  if (j < 24576) {  // w1T[t][n][k] = w1_t[k][n]   (n<128, k<64)
    int t = j >> 13, jj = j & 8191, n = jj >> 6, k = jj & 63;
    const float* w1 = t == 0 ? w1s : (t == 1 ? w1a : w1n);
    w1T[j] = f2bf(w1[k * 128 + n]);
    return;
  }
  j -= 24576;
  if (j < 98304) {  // w2T[t][n][k] = w2_t[k][n]   (n<256, k<128)
    int t = j >> 15, jj = j & 32767, n = jj >> 7, k = jj & 127;
    const float* w2 = t == 0 ? w2s : (t == 1 ? w2a : w2n);
    w2T[j] = f2bf(w2[k * 256 + n]);
    return;
  }
  j -= 98304;
  if (j < 196608) {  // gT[n][t*256+k] = g_t[k][n]
    int n = j / 768, q = j % 768, t = q >> 8, k = q & 255;
    const float* g = t == 0 ? gs : (t == 1 ? ga : gn);
    gT[j] = f2bf(g[k * 256 + n]);
  }
}

// --------------------------- he = electrons @ h_w ---------------------------
__global__ __launch_bounds__(256) void k_he(const float* elec, const u16* hwT,
                                            u16* he) {
  __shared__ char As[8192], Bs[8192];
  f32x4 acc[4][4];
  zero_acc(acc);
  const int m0 = blockIdx.x * 128, n0 = blockIdx.y * 128;
  gemm_core<true>(nullptr, 0, elec + (long)m0 * 256, 256,
                  (const char*)hwT + (long)n0 * 512, 512, 256, As, Bs, acc,
                  threadIdx.x);
  const int l = threadIdx.x & 63, lane15 = l & 15, quad = l >> 4,
            wv = threadIdx.x >> 6;
  const int mw = (wv >> 1) * 64, nw = (wv & 1) * 64;
#pragma unroll
  for (int mi = 0; mi < 4; ++mi)
#pragma unroll
    for (int r = 0; r < 4; ++r) {
      const int row = m0 + mw + mi * 16 + quad * 4 + r;
#pragma unroll
      for (int ni = 0; ni < 4; ++ni) {
        const int col = n0 + nw + ni * 16 + lane15;
        he[row * 256 + col] = f2bf(acc[mi][ni][r]);
      }
    }
}

// ------------------- midact = SSP(dist @ w1 + b1), per type -----------------
__global__ __launch_bounds__(256) void k_mlp1(
    const float* d0, const float* d1, const float* d2, const float* b0,
    const float* b1p, const float* b2, const u16* w1T, u16* midact) {
  __shared__ char As[8192], Bs[8192];
  const int t = blockIdx.z;
  const float* dist = t == 0 ? d0 : (t == 1 ? d1 : d2);
  const float* bias = t == 0 ? b0 : (t == 1 ? b1p : b2);
  f32x4 acc[4][4];
  zero_acc(acc);
  const int m0 = blockIdx.x * 128;  // N=128 -> single col block
  gemm_core<true>(nullptr, 0, dist + (long)m0 * 64, 64,
                  (const char*)(w1T + t * 8192), 128, 64, As, Bs, acc,
                  threadIdx.x);
  const int l = threadIdx.x & 63, lane15 = l & 15, quad = l >> 4,
            wv = threadIdx.x >> 6;
  const int mw = (wv >> 1) * 64, nw = (wv & 1) * 64;
  u16* mout = midact + (size_t)t * ((size_t)NEDGE * MID);
#pragma unroll
  for (int mi = 0; mi < 4; ++mi)
#pragma unroll
    for (int r = 0; r < 4; ++r) {
      const int row = m0 + mw + mi * 16 + quad * 4 + r;  // edge index
#pragma unroll
      for (int ni = 0; ni < 4; ++ni) {
        const int col = nw + ni * 16 + lane15;  // mid index
        float x = acc[mi][ni][r] + bias[col];
        mout[(size_t)row * MID + col] = f2bf(ssp(x));
      }
    }
}

// ------- fused: we = midact @ w2; z[recv] += we * src[sender]  (atomics) ----
__global__ __launch_bounds__(256) void k_scat(
    const u16* midact, const u16* w2T, const u16* he, const float* nucf,
    const int* s0, const int* s1, const int* s2, const int* r0, const int* r1,
    const int* r2, float* z) {
  __shared__ char As[8192], Bs[8192];
  const int t = blockIdx.z;
  const int* snd = t == 0 ? s0 : (t == 1 ? s1 : s2);
  const int* rcv = t == 0 ? r0 : (t == 1 ? r1 : r2);
  f32x4 acc[4][4];
  zero_acc(acc);
  const int m0 = blockIdx.x * 128, n0 = blockIdx.y * 128;
  gemm_core<false>((const char*)(midact + (size_t)t * ((size_t)NEDGE * MID)) +
                       (long)m0 * 256, 256, nullptr, 0,
                   (const char*)(w2T + t * 32768) + (long)n0 * 256, 256, 128,
                   As, Bs, acc, threadIdx.x);
  const int l = threadIdx.x & 63, lane15 = l & 15, quad = l >> 4,
            wv = threadIdx.x >> 6;
  const int mw = (wv >> 1) * 64, nw = (wv & 1) * 64;
#pragma unroll
  for (int mi = 0; mi < 4; ++mi)
#pragma unroll
    for (int r = 0; r < 4; ++r) {
      const int e = m0 + mw + mi * 16 + quad * 4 + r;  // edge index
      const int se = snd[e];
      const int re = rcv[e];
      float* zrow = z + (size_t)re * 768 + t * 256;
#pragma unroll
      for (int ni = 0; ni < 4; ++ni) {
        const int c = n0 + nw + ni * 16 + lane15;  // ker index
        const float s = (t == 2) ? nucf[(size_t)se * 256 + c]
                                 : bf2f(he[(size_t)se * 256 + c]);
        const float v = acc[mi][ni][r] * s;
        unsafeAtomicAdd(zrow + c, v);  // HW global_atomic_add_f32
      }
    }
}

// ----------------------------- z (f32) -> bf16 ------------------------------
__global__ __launch_bounds__(256) void k_cvt(const float4* z, ushort4* zbf) {
  const int i = blockIdx.x * 256 + threadIdx.x;
  float4 v = z[i];
  ushort4 o;
  o.x = f2bf(v.x);
  o.y = f2bf(v.y);
  o.z = f2bf(v.z);
  o.w = f2bf(v.w);
  zbf[i] = o;
}

// ------------- out = electrons_f32 + zbf[8192,768] @ gT^T  (f32) ------------
__global__ __launch_bounds__(256) void k_final(const u16* zbf, const u16* gT,
                                               const float* elec, float* out) {
  __shared__ char As[8192], Bs[8192];
  f32x4 acc[4][4];
  zero_acc(acc);
  const int m0 = blockIdx.x * 128, n0 = blockIdx.y * 128;
  gemm_core<false>((const char*)zbf + (long)m0 * 1536, 1536, nullptr, 0,
                   (const char*)gT + (long)n0 * 1536, 1536, 768, As, Bs, acc,
                   threadIdx.x);
  const int l = threadIdx.x & 63, lane15 = l & 15, quad = l >> 4,
            wv = threadIdx.x >> 6;
  const int mw = (wv >> 1) * 64, nw = (wv & 1) * 64;
#pragma unroll
  for (int mi = 0; mi < 4; ++mi)
#pragma unroll
    for (int r = 0; r < 4; ++r) {
      const int row = m0 + mw + mi * 16 + quad * 4 + r;
#pragma unroll
      for (int ni = 0; ni < 4; ++ni) {
        const int col = n0 + nw + ni * 16 + lane15;
        out[row * 256 + col] = acc[mi][ni][r] + elec[row * 256 + col];
      }
    }
}

// ---------------------------------------------------------------------------
extern "C" void kernel_launch(void* const* d_in, const int* in_sizes, int n_in,
                              void* d_out, int out_size, void* d_ws,
                              size_t ws_size, hipStream_t stream) {
  // Input index maps: setup_inputs() dict order (grouped per label) vs
  // reference signature order (defensive). Distinguish via in_sizes[3]:
  // dict -> w1_same (8192), signature -> dist_anti (8388608).
  int I_dist[3], I_w1[3], I_b1[3], I_w2[3], I_g[3], I_hw;
  if (in_sizes[3] == 64 * 128) {  // dict order
    for (int t = 0; t < 3; ++t) {
      I_dist[t] = 2 + t * 5 + 0;
      I_w1[t] = 2 + t * 5 + 1;
      I_b1[t] = 2 + t * 5 + 2;
      I_w2[t] = 2 + t * 5 + 3;
      I_g[t] = 2 + t * 5 + 4;
    }
    I_hw = 17;
  } else {  // reference signature order
    I_dist[0] = 2; I_dist[1] = 3; I_dist[2] = 4;
    I_w1[0] = 5;  I_b1[0] = 6;  I_w2[0] = 7;
    I_w1[1] = 8;  I_b1[1] = 9;  I_w2[1] = 10;
    I_w1[2] = 11; I_b1[2] = 12; I_w2[2] = 13;
    I_g[0] = 14; I_g[1] = 15; I_g[2] = 16;
    I_hw = 17;
  }
  const int I_snd[3] = {18, 19, 20};
  const int I_rcv[3] = {21, 22, 23};

  char* ws = (char*)d_ws;
  // workspace layout (bytes, 256B aligned). Total ~137 MB.
  u16* he = (u16*)(ws + 0);             //   4,194,304
  u16* hwT = (u16*)(ws + 4194304);      //     131,072
  u16* w1T = (u16*)(ws + 4325376);      //      49,152
  u16* w2T = (u16*)(ws + 4374528);      //     196,608
  u16* gT = (u16*)(ws + 4571136);       //     393,216
  u16* midact = (u16*)(ws + 4964352);   // 100,663,296
  float* z = (float*)(ws + 105627648);  //  25,165,824
  u16* zbf = (u16*)(ws + 130793472);    //  12,582,912

  const float* elec = (const float*)d_in[0];
  const float* nuc = (const float*)d_in[1];

  k_zero<<<(N_ELEC * 768 / 4) / 256, 256, 0, stream>>>((float4*)z);

  k_prep<<<1504, 256, 0, stream>>>(
      (const float*)d_in[I_hw], (const float*)d_in[I_w1[0]],
      (const float*)d_in[I_w1[1]], (const float*)d_in[I_w1[2]],
      (const float*)d_in[I_w2[0]], (const float*)d_in[I_w2[1]],
      (const float*)d_in[I_w2[2]], (const float*)d_in[I_g[0]],
      (const float*)d_in[I_g[1]], (const float*)d_in[I_g[2]], hwT, w1T, w2T,
      gT);

  k_he<<<dim3(N_ELEC / 128, 2), 256, 0, stream>>>(elec, hwT, he);

  k_mlp1<<<dim3(NEDGE / 128, 1, 3), 256, 0, stream>>>(
      (const float*)d_in[I_dist[0]], (const float*)d_in[I_dist[1]],
      (const float*)d_in[I_dist[2]], (const float*)d_in[I_b1[0]],
      (const float*)d_in[I_b1[1]], (const float*)d_in[I_b1[2]], w1T, midact);

  k_scat<<<dim3(NEDGE / 128, 2, 3), 256, 0, stream>>>(
      midact, w2T, he, nuc, (const int*)d_in[I_snd[0]],
      (const int*)d_in[I_snd[1]], (const int*)d_in[I_snd[2]],
      (const int*)d_in[I_rcv[0]], (const int*)d_in[I_rcv[1]],
      (const int*)d_in[I_rcv[2]], z);

  k_cvt<<<(N_ELEC * 768 / 4) / 256, 256, 0, stream>>>((const float4*)z,
                                                      (ushort4*)zbf);

  k_final<<<dim3(N_ELEC / 128, 2), 256, 0, stream>>>(zbf, gT, elec,
                                                     (float*)d_out);
}

// Round 3
// 750.133 us; speedup vs baseline: 1.0230x; 1.0230x over previous
//
#include <hip/hip_runtime.h>
#include <stdint.h>

// ---------------------------------------------------------------------------
// SchNetLayer on MI355X (gfx950).
// I/O dtypes: float tensors are FLOAT32, indices int32. Internal: bf16 MFMA.
//
// Round-2 lesson: fused atomic scatter (100.7M f32 atomics) ran at 2.7%
// MfmaUtil / 18% HBM — atomic-rate bound. Round 3 eliminates atomics:
// counting-sort edges by receiver, write weh in sorted order with plain
// stores, then CSR segment-sum (contiguous streaming reads).
//
// Pipeline:
//   k_zeroI  : cnt = 0
//   k_hist   : cnt[t][recv[e]]++                         (393K int atomics)
//   k_scan   : rowptr/cursor = exclusive_scan(cnt)       (1 block/type)
//   k_place  : perm[t][pos]=e, snd_s[t][pos]=senders[e]  (sorted by receiver)
//   k_prep   : cast+transpose weights -> bf16 ws
//   k_he     : he = bf16(electrons) @ h_w                [8192,256] bf16
//   k_mlp1   : midact[pos] = SSP(bf16(dist[perm[pos]]) @ w1 + b1)  (sorted)
//   per type t:
//     k_weh  : weh[pos] = (midact @ w2)[pos] * src[snd_s[pos]]  (plain stores)
//     k_gather: zbf[r][t*256+c] = sum_{pos in [rowptr[r],rowptr[r+1])} weh[pos][c]
//   k_final  : out = electrons + zbf[8192,768] @ g_catT  f32 out
// ---------------------------------------------------------------------------

#define N_ELEC 8192
#define N_NUC  512
#define EMB    256
#define KER    256
#define DF     64
#define MID    128
#define NEDGE  131072
#define RPS    8256  // rowptr per-type stride (ints), >= 8193

using u16 = unsigned short;
typedef short short8 __attribute__((ext_vector_type(8)));
typedef float f32x4 __attribute__((ext_vector_type(4)));

__device__ __forceinline__ float bf2f(u16 h) {
  return __uint_as_float(((unsigned)h) << 16);
}
__device__ __forceinline__ u16 f2bf(float f) {
  unsigned u = __float_as_uint(f);
  return (u16)((u + 0x7FFFu + ((u >> 16) & 1u)) >> 16);  // RNE
}
__device__ __forceinline__ float ssp(float x) {
  float sp = (x > 20.0f) ? x : log1pf(expf(x));
  return sp - 0.69314718055994531f;
}

// Stage a 128x32 bf16 tile (row-major, row stride bytes) into an 8 KB LDS
// buffer [128][32] bf16 (64 B rows) via global_load_lds (width 16).
__device__ __forceinline__ void stage_tile(const char* g0, long stride,
                                           char* lds, int tid) {
  const int l = tid & 63, w = tid >> 6;
#pragma unroll
  for (int c = 0; c < 2; ++c) {
    const int r = c * 64 + w * 16 + (l >> 2);
    const int cb = (l & 3) * 16;
    const char* g = g0 + (long)r * stride + cb;
    char* dst = lds + c * 4096 + w * 1024;  // wave-uniform base
    __builtin_amdgcn_global_load_lds(
        (const __attribute__((address_space(1))) unsigned*)g,
        (__attribute__((address_space(3))) unsigned*)dst, 16, 0, 0);
  }
}

// Stage a 128x32 tile of an f32 matrix into [128][32]-bf16 LDS, converting in
// VGPRs. rowidx (nullable) gathers arbitrary source rows (receiver-sort).
__device__ __forceinline__ void stage_f32(const float* g0, int stride_e,
                                          int kt, const int* rowidx, char* lds,
                                          int tid) {
#pragma unroll
  for (int k = 0; k < 8; ++k) {
    const int idx2 = k * 256 + tid;  // 2048 float2 slots
    const int row = idx2 >> 4, cp = idx2 & 15;
    const long gr = rowidx ? (long)rowidx[row] : (long)row;
    const float2 v = *(const float2*)(g0 + gr * stride_e + kt + cp * 2);
    const unsigned p = ((unsigned)f2bf(v.y) << 16) | (unsigned)f2bf(v.x);
    *(unsigned*)(lds + row * 64 + cp * 4) = p;
  }
}

// 128x128 tile GEMM: C = A[128,K] * Bt[128,K]^T, bf16 MFMA 16x16x32,
// 4 waves in 2x2 quadrants, 4x4 fragments each.
template <bool A_F32>
__device__ __forceinline__ void gemm_core(const char* A0, long as_bytes,
                                          const float* Af, int as_elems,
                                          const int* Aidx, const char* B0,
                                          long bs, int K, char* As, char* Bs,
                                          f32x4 acc[4][4], int tid) {
  const int l = tid & 63, lane15 = l & 15, quad = l >> 4, wv = tid >> 6;
  const int mw = (wv >> 1) * 64, nw = (wv & 1) * 64;
  for (int kt = 0; kt < K; kt += 32) {
    if (A_F32)
      stage_f32(Af, as_elems, kt, Aidx, As, tid);
    else
      stage_tile(A0 + (long)kt * 2, as_bytes, As, tid);
    stage_tile(B0 + (long)kt * 2, bs, Bs, tid);
    __syncthreads();
    short8 af[4], bf[4];
#pragma unroll
    for (int i = 0; i < 4; ++i) {
      af[i] = *(const short8*)(As + (mw + i * 16 + lane15) * 64 + quad * 16);
      bf[i] = *(const short8*)(Bs + (nw + i * 16 + lane15) * 64 + quad * 16);
    }
#pragma unroll
    for (int mi = 0; mi < 4; ++mi)
#pragma unroll
      for (int ni = 0; ni < 4; ++ni)
        acc[mi][ni] = __builtin_amdgcn_mfma_f32_16x16x32_bf16(
            af[mi], bf[ni], acc[mi][ni], 0, 0, 0);
    __syncthreads();
  }
}

__device__ __forceinline__ void zero_acc(f32x4 acc[4][4]) {
#pragma unroll
  for (int i = 0; i < 4; ++i)
#pragma unroll
    for (int j = 0; j < 4; ++j) acc[i][j] = (f32x4){0.f, 0.f, 0.f, 0.f};
}

// ----------------------------- sort kernels ---------------------------------
__global__ __launch_bounds__(256) void k_zeroI(int* cnt) {
  cnt[blockIdx.x * 256 + threadIdx.x] = 0;
}

__global__ __launch_bounds__(256) void k_hist(const int* r0, const int* r1,
                                              const int* r2, int* cnt) {
  const int t = blockIdx.z;
  const int* rcv = t == 0 ? r0 : (t == 1 ? r1 : r2);
  const int e = blockIdx.x * 256 + threadIdx.x;
  atomicAdd(&cnt[t * N_ELEC + rcv[e]], 1);
}

__global__ __launch_bounds__(256) void k_scan(const int* cnt, int* rowptr,
                                              int* cursor) {
  const int t = blockIdx.x, tid = threadIdx.x;
  __shared__ int part[256];
  const int* c = cnt + t * N_ELEC;
  int s = 0;
#pragma unroll
  for (int i = 0; i < 32; ++i) s += c[tid * 32 + i];
  part[tid] = s;
  __syncthreads();
  for (int off = 1; off < 256; off <<= 1) {
    int v = (tid >= off) ? part[tid - off] : 0;
    __syncthreads();
    part[tid] += v;
    __syncthreads();
  }
  int run = (tid == 0) ? 0 : part[tid - 1];
  int* rp = rowptr + t * RPS;
  int* cu = cursor + t * N_ELEC;
  for (int i = 0; i < 32; ++i) {
    rp[tid * 32 + i] = run;
    cu[tid * 32 + i] = run;
    run += c[tid * 32 + i];
  }
  if (tid == 255) rp[N_ELEC] = run;  // = NEDGE
}

__global__ __launch_bounds__(256) void k_place(const int* r0, const int* r1,
                                               const int* r2, const int* s0,
                                               const int* s1, const int* s2,
                                               int* cursor, int* perm,
                                               int* snd_s) {
  const int t = blockIdx.z;
  const int* rcv = t == 0 ? r0 : (t == 1 ? r1 : r2);
  const int* snd = t == 0 ? s0 : (t == 1 ? s1 : s2);
  const int e = blockIdx.x * 256 + threadIdx.x;
  const int pos = atomicAdd(&cursor[t * N_ELEC + rcv[e]], 1);
  perm[t * NEDGE + pos] = e;
  snd_s[t * NEDGE + pos] = snd[e];
}

// ------------------ prep: f32 weights -> transposed bf16 --------------------
// hwT [KER][EMB], w1T [3][MID][DF], w2T [3][KER][MID], gT [EMB][3*KER]
__global__ __launch_bounds__(256) void k_prep(
    const float* h_w, const float* w1s, const float* w1a, const float* w1n,
    const float* w2s, const float* w2a, const float* w2n, const float* gs,
    const float* ga, const float* gn, u16* hwT, u16* w1T, u16* w2T, u16* gT) {
  int i = blockIdx.x * 256 + threadIdx.x;
  if (i < 65536) {
    int n = i >> 8, k = i & 255;
    hwT[i] = f2bf(h_w[k * 256 + n]);
    return;
  }
  int j = i - 65536;
  if (j < 24576) {
    int t = j >> 13, jj = j & 8191, n = jj >> 6, k = jj & 63;
    const float* w1 = t == 0 ? w1s : (t == 1 ? w1a : w1n);
    w1T[j] = f2bf(w1[k * 128 + n]);
    return;
  }
  j -= 24576;
  if (j < 98304) {
    int t = j >> 15, jj = j & 32767, n = jj >> 7, k = jj & 127;
    const float* w2 = t == 0 ? w2s : (t == 1 ? w2a : w2n);
    w2T[j] = f2bf(w2[k * 256 + n]);
    return;
  }
  j -= 98304;
  if (j < 196608) {
    int n = j / 768, q = j % 768, t = q >> 8, k = q & 255;
    const float* g = t == 0 ? gs : (t == 1 ? ga : gn);
    gT[j] = f2bf(g[k * 256 + n]);
  }
}

// --------------------------- he = electrons @ h_w ---------------------------
__global__ __launch_bounds__(256) void k_he(const float* elec, const u16* hwT,
                                            u16* he) {
  __shared__ char As[8192], Bs[8192];
  f32x4 acc[4][4];
  zero_acc(acc);
  const int m0 = blockIdx.x * 128, n0 = blockIdx.y * 128;
  gemm_core<true>(nullptr, 0, elec + (long)m0 * 256, 256, nullptr,
                  (const char*)hwT + (long)n0 * 512, 512, 256, As, Bs, acc,
                  threadIdx.x);
  const int l = threadIdx.x & 63, lane15 = l & 15, quad = l >> 4,
            wv = threadIdx.x >> 6;
  const int mw = (wv >> 1) * 64, nw = (wv & 1) * 64;
#pragma unroll
  for (int mi = 0; mi < 4; ++mi)
#pragma unroll
    for (int r = 0; r < 4; ++r) {
      const int row = m0 + mw + mi * 16 + quad * 4 + r;
#pragma unroll
      for (int ni = 0; ni < 4; ++ni) {
        const int col = n0 + nw + ni * 16 + lane15;
        he[row * 256 + col] = f2bf(acc[mi][ni][r]);
      }
    }
}

// ---- midact[pos] = SSP(dist[perm[pos]] @ w1 + b1), receiver-sorted order ---
__global__ __launch_bounds__(256) void k_mlp1(
    const float* d0, const float* d1, const float* d2, const float* b0,
    const float* b1p, const float* b2, const u16* w1T, const int* perm,
    u16* midact) {
  __shared__ char As[8192], Bs[8192];
  const int t = blockIdx.z;
  const float* dist = t == 0 ? d0 : (t == 1 ? d1 : d2);
  const float* bias = t == 0 ? b0 : (t == 1 ? b1p : b2);
  f32x4 acc[4][4];
  zero_acc(acc);
  const int m0 = blockIdx.x * 128;
  gemm_core<true>(nullptr, 0, dist, 64, perm + t * NEDGE + m0,
                  (const char*)(w1T + t * 8192), 128, 64, As, Bs, acc,
                  threadIdx.x);
  const int l = threadIdx.x & 63, lane15 = l & 15, quad = l >> 4,
            wv = threadIdx.x >> 6;
  const int mw = (wv >> 1) * 64, nw = (wv & 1) * 64;
  u16* mout = midact + (size_t)t * ((size_t)NEDGE * MID);
#pragma unroll
  for (int mi = 0; mi < 4; ++mi)
#pragma unroll
    for (int r = 0; r < 4; ++r) {
      const int row = m0 + mw + mi * 16 + quad * 4 + r;  // sorted position
#pragma unroll
      for (int ni = 0; ni < 4; ++ni) {
        const int col = nw + ni * 16 + lane15;
        float x = acc[mi][ni][r] + bias[col];
        mout[(size_t)row * MID + col] = f2bf(ssp(x));
      }
    }
}

// ------ weh[pos] = (midact @ w2)[pos] * src[snd_s[pos]]  (plain stores) -----
__global__ __launch_bounds__(256) void k_weh(const u16* midact_t,
                                             const u16* w2T_t, const u16* he,
                                             const float* nucf,
                                             const int* snd_s_t, int is_nuc,
                                             u16* weh) {
  __shared__ char As[8192], Bs[8192];
  f32x4 acc[4][4];
  zero_acc(acc);
  const int m0 = blockIdx.x * 128, n0 = blockIdx.y * 128;
  gemm_core<false>((const char*)midact_t + (long)m0 * 256, 256, nullptr, 0,
                   nullptr, (const char*)w2T_t + (long)n0 * 256, 256, 128, As,
                   Bs, acc, threadIdx.x);
  const int l = threadIdx.x & 63, lane15 = l & 15, quad = l >> 4,
            wv = threadIdx.x >> 6;
  const int mw = (wv >> 1) * 64, nw = (wv & 1) * 64;
#pragma unroll
  for (int mi = 0; mi < 4; ++mi)
#pragma unroll
    for (int r = 0; r < 4; ++r) {
      const int e = m0 + mw + mi * 16 + quad * 4 + r;  // sorted position
      const int se = snd_s_t[e];
      u16* wrow = weh + (size_t)e * 256;
#pragma unroll
      for (int ni = 0; ni < 4; ++ni) {
        const int c = n0 + nw + ni * 16 + lane15;
        const float s = is_nuc ? nucf[(size_t)se * 256 + c]
                               : bf2f(he[(size_t)se * 256 + c]);
        wrow[c] = f2bf(acc[mi][ni][r] * s);
      }
    }
}

// --- zbf[r][t*256+c] = sum over weh rows in [rowptr[r], rowptr[r+1]) --------
// Block: 2 receivers x 128 col-pairs; contiguous streaming reads of weh.
__global__ __launch_bounds__(256) void k_gather(const u16* weh,
                                                const int* rowptr_t, int t,
                                                u16* zbf) {
  const int tid = threadIdx.x;
  const int r = blockIdx.x * 2 + (tid >> 7);
  const int cp = tid & 127;
  const int start = rowptr_t[r], end = rowptr_t[r + 1];
  float a0 = 0.f, a1 = 0.f;
  for (int i = start; i < end; ++i) {
    const unsigned p = *(const unsigned*)(weh + (size_t)i * 256 + cp * 2);
    a0 += bf2f((u16)(p & 0xffff));
    a1 += bf2f((u16)(p >> 16));
  }
  const unsigned o = ((unsigned)f2bf(a1) << 16) | (unsigned)f2bf(a0);
  *(unsigned*)(zbf + (size_t)r * 768 + t * 256 + cp * 2) = o;
}

// ------------- out = electrons_f32 + zbf[8192,768] @ gT^T  (f32) ------------
__global__ __launch_bounds__(256) void k_final(const u16* zbf, const u16* gT,
                                               const float* elec, float* out) {
  __shared__ char As[8192], Bs[8192];
  f32x4 acc[4][4];
  zero_acc(acc);
  const int m0 = blockIdx.x * 128, n0 = blockIdx.y * 128;
  gemm_core<false>((const char*)zbf + (long)m0 * 1536, 1536, nullptr, 0,
                   nullptr, (const char*)gT + (long)n0 * 1536, 1536, 768, As,
                   Bs, acc, threadIdx.x);
  const int l = threadIdx.x & 63, lane15 = l & 15, quad = l >> 4,
            wv = threadIdx.x >> 6;
  const int mw = (wv >> 1) * 64, nw = (wv & 1) * 64;
#pragma unroll
  for (int mi = 0; mi < 4; ++mi)
#pragma unroll
    for (int r = 0; r < 4; ++r) {
      const int row = m0 + mw + mi * 16 + quad * 4 + r;
#pragma unroll
      for (int ni = 0; ni < 4; ++ni) {
        const int col = n0 + nw + ni * 16 + lane15;
        out[row * 256 + col] = acc[mi][ni][r] + elec[row * 256 + col];
      }
    }
}

// ---------------------------------------------------------------------------
extern "C" void kernel_launch(void* const* d_in, const int* in_sizes, int n_in,
                              void* d_out, int out_size, void* d_ws,
                              size_t ws_size, hipStream_t stream) {
  int I_dist[3], I_w1[3], I_b1[3], I_w2[3], I_g[3], I_hw;
  if (in_sizes[3] == 64 * 128) {  // setup_inputs() dict order
    for (int t = 0; t < 3; ++t) {
      I_dist[t] = 2 + t * 5 + 0;
      I_w1[t] = 2 + t * 5 + 1;
      I_b1[t] = 2 + t * 5 + 2;
      I_w2[t] = 2 + t * 5 + 3;
      I_g[t] = 2 + t * 5 + 4;
    }
    I_hw = 17;
  } else {  // reference signature order
    I_dist[0] = 2; I_dist[1] = 3; I_dist[2] = 4;
    I_w1[0] = 5;  I_b1[0] = 6;  I_w2[0] = 7;
    I_w1[1] = 8;  I_b1[1] = 9;  I_w2[1] = 10;
    I_w1[2] = 11; I_b1[2] = 12; I_w2[2] = 13;
    I_g[0] = 14; I_g[1] = 15; I_g[2] = 16;
    I_hw = 17;
  }
  const int I_snd[3] = {18, 19, 20};
  const int I_rcv[3] = {21, 22, 23};

  char* ws = (char*)d_ws;
  // workspace layout (bytes). Total ~189 MB.
  u16* he = (u16*)(ws + 0);                   //   4,194,304
  u16* hwT = (u16*)(ws + 4194304);            //     131,072
  u16* w1T = (u16*)(ws + 4325376);            //      49,152
  u16* w2T = (u16*)(ws + 4374528);            //     196,608
  u16* gT = (u16*)(ws + 4571136);             //     393,216
  u16* midact = (u16*)(ws + 4964352);         // 100,663,296
  u16* weh = (u16*)(ws + 105627648);          //  67,108,864 (per-type, reused)
  u16* zbf = (u16*)(ws + 172736512);          //  12,582,912
  int* cnt = (int*)(ws + 185319424);          //      98,304
  int* rowptr = (int*)(ws + 185417728);       //      99,072
  int* cursor = (int*)(ws + 185516800);       //      98,304
  int* perm = (int*)(ws + 185615104);         //   1,572,864
  int* snd_s = (int*)(ws + 187187968);        //   1,572,864

  const float* elec = (const float*)d_in[0];
  const float* nuc = (const float*)d_in[1];
  const int* s0 = (const int*)d_in[I_snd[0]];
  const int* s1 = (const int*)d_in[I_snd[1]];
  const int* s2 = (const int*)d_in[I_snd[2]];
  const int* r0 = (const int*)d_in[I_rcv[0]];
  const int* r1 = (const int*)d_in[I_rcv[1]];
  const int* r2 = (const int*)d_in[I_rcv[2]];

  // --- counting sort by receiver, per type ---
  k_zeroI<<<3 * N_ELEC / 256, 256, 0, stream>>>(cnt);
  k_hist<<<dim3(NEDGE / 256, 1, 3), 256, 0, stream>>>(r0, r1, r2, cnt);
  k_scan<<<3, 256, 0, stream>>>(cnt, rowptr, cursor);
  k_place<<<dim3(NEDGE / 256, 1, 3), 256, 0, stream>>>(r0, r1, r2, s0, s1, s2,
                                                       cursor, perm, snd_s);

  k_prep<<<1504, 256, 0, stream>>>(
      (const float*)d_in[I_hw], (const float*)d_in[I_w1[0]],
      (const float*)d_in[I_w1[1]], (const float*)d_in[I_w1[2]],
      (const float*)d_in[I_w2[0]], (const float*)d_in[I_w2[1]],
      (const float*)d_in[I_w2[2]], (const float*)d_in[I_g[0]],
      (const float*)d_in[I_g[1]], (const float*)d_in[I_g[2]], hwT, w1T, w2T,
      gT);

  k_he<<<dim3(N_ELEC / 128, 2), 256, 0, stream>>>(elec, hwT, he);

  k_mlp1<<<dim3(NEDGE / 128, 1, 3), 256, 0, stream>>>(
      (const float*)d_in[I_dist[0]], (const float*)d_in[I_dist[1]],
      (const float*)d_in[I_dist[2]], (const float*)d_in[I_b1[0]],
      (const float*)d_in[I_b1[1]], (const float*)d_in[I_b1[2]], w1T, perm,
      midact);

  for (int t = 0; t < 3; ++t) {
    k_weh<<<dim3(NEDGE / 128, 2), 256, 0, stream>>>(
        midact + (size_t)t * ((size_t)NEDGE * MID), w2T + t * 32768, he, nuc,
        snd_s + t * NEDGE, t == 2 ? 1 : 0, weh);
    k_gather<<<N_ELEC / 2, 256, 0, stream>>>(weh, rowptr + t * RPS, t, zbf);
  }

  k_final<<<dim3(N_ELEC / 128, 2), 256, 0, stream>>>(zbf, gT, elec,
                                                     (float*)d_out);
}

// Round 4
// 566.410 us; speedup vs baseline: 1.3549x; 1.3244x over previous
//
#include <hip/hip_runtime.h>
#include <stdint.h>

// ---------------------------------------------------------------------------
// SchNetLayer on MI355X (gfx950).
// I/O: float tensors f32, indices int32. Internal: bf16 MFMA.
//
// R2 lesson: atomic scatter = atomic-rate bound (2.7% MFMA, 18% HBM) -> sort.
// R3 lesson: k_mlp1 251us @ 75% VALUBusy -> precise libm softplus dominated.
// R4: fast ssp via native v_exp/v_log; lean staging in k_mlp1; uint4 k_gather.
//
// Pipeline:
//   sort:  k_zeroI, k_hist, k_scan, k_place   (counting sort by receiver)
//   k_prep : cast+transpose weights -> bf16 ws
//   k_he   : he = bf16(electrons) @ h_w                [8192,256] bf16
//   k_mlp1 : midact[pos] = SSP(bf16(dist[perm[pos]]) @ w1 + b1)  (sorted)
//   per type t:
//     k_weh  : weh[pos] = (midact @ w2)[pos] * src[snd_s[pos]]  (plain stores)
//     k_gather: zbf[r][t*256+:] = sum of weh rows in [rowptr[r],rowptr[r+1])
//   k_final: out = electrons + zbf[8192,768] @ g_catT  f32 out
// ---------------------------------------------------------------------------

#define N_ELEC 8192
#define N_NUC  512
#define EMB    256
#define KER    256
#define DF     64
#define MID    128
#define NEDGE  131072
#define RPS    8256  // rowptr per-type stride (ints), >= 8193

using u16 = unsigned short;
typedef short short8 __attribute__((ext_vector_type(8)));
typedef float f32x4 __attribute__((ext_vector_type(4)));

__device__ __forceinline__ float bf2f(u16 h) {
  return __uint_as_float(((unsigned)h) << 16);
}
__device__ __forceinline__ u16 f2bf(float f) {
  unsigned u = __float_as_uint(f);
  return (u16)((u + 0x7FFFu + ((u >> 16) & 1u)) >> 16);  // RNE
}
__device__ __forceinline__ unsigned pkbf(float a, float b) {
  return ((unsigned)f2bf(b) << 16) | (unsigned)f2bf(a);
}
// fast shifted softplus: log(0.5 e^x + 0.5), stable form, native v_exp/v_log.
// |err| <= ~1e-6 abs — far below bf16 grid (2^-9 rel).
__device__ __forceinline__ float ssp_fast(float x) {
  const float e = __expf(-fabsf(x));
  return fmaxf(x, 0.f) + __logf(fmaf(0.5f, e, 0.5f));
}

// Stage a 128x32 bf16 tile (row-major, row stride bytes) into an 8 KB LDS
// buffer [128][32] bf16 (64 B rows) via global_load_lds (width 16).
__device__ __forceinline__ void stage_tile(const char* g0, long stride,
                                           char* lds, int tid) {
  const int l = tid & 63, w = tid >> 6;
#pragma unroll
  for (int c = 0; c < 2; ++c) {
    const int r = c * 64 + w * 16 + (l >> 2);
    const int cb = (l & 3) * 16;
    const char* g = g0 + (long)r * stride + cb;
    char* dst = lds + c * 4096 + w * 1024;  // wave-uniform base
    __builtin_amdgcn_global_load_lds(
        (const __attribute__((address_space(1))) unsigned*)g,
        (__attribute__((address_space(3))) unsigned*)dst, 16, 0, 0);
  }
}

// Stage a 128x32 tile of an f32 matrix into [128][32]-bf16 LDS (f32->bf16 in
// VGPRs, coalesced float2 loads).
__device__ __forceinline__ void stage_f32(const float* g0, int stride_e,
                                          int kt, char* lds, int tid) {
#pragma unroll
  for (int k = 0; k < 8; ++k) {
    const int idx2 = k * 256 + tid;
    const int row = idx2 >> 4, cp = idx2 & 15;
    const float2 v = *(const float2*)(g0 + (long)row * stride_e + kt + cp * 2);
    *(unsigned*)(lds + row * 64 + cp * 4) = pkbf(v.x, v.y);
  }
}

// 128x128 tile GEMM: C = A[128,K] * Bt[128,K]^T, bf16 MFMA 16x16x32,
// 4 waves in 2x2 quadrants, 4x4 fragments each.
template <bool A_F32>
__device__ __forceinline__ void gemm_core(const char* A0, long as_bytes,
                                          const float* Af, int as_elems,
                                          const char* B0, long bs, int K,
                                          char* As, char* Bs, f32x4 acc[4][4],
                                          int tid) {
  const int l = tid & 63, lane15 = l & 15, quad = l >> 4, wv = tid >> 6;
  const int mw = (wv >> 1) * 64, nw = (wv & 1) * 64;
  for (int kt = 0; kt < K; kt += 32) {
    if (A_F32)
      stage_f32(Af, as_elems, kt, As, tid);
    else
      stage_tile(A0 + (long)kt * 2, as_bytes, As, tid);
    stage_tile(B0 + (long)kt * 2, bs, Bs, tid);
    __syncthreads();
    short8 af[4], bf[4];
#pragma unroll
    for (int i = 0; i < 4; ++i) {
      af[i] = *(const short8*)(As + (mw + i * 16 + lane15) * 64 + quad * 16);
      bf[i] = *(const short8*)(Bs + (nw + i * 16 + lane15) * 64 + quad * 16);
    }
#pragma unroll
    for (int mi = 0; mi < 4; ++mi)
#pragma unroll
      for (int ni = 0; ni < 4; ++ni)
        acc[mi][ni] = __builtin_amdgcn_mfma_f32_16x16x32_bf16(
            af[mi], bf[ni], acc[mi][ni], 0, 0, 0);
    __syncthreads();
  }
}

__device__ __forceinline__ void zero_acc(f32x4 acc[4][4]) {
#pragma unroll
  for (int i = 0; i < 4; ++i)
#pragma unroll
    for (int j = 0; j < 4; ++j) acc[i][j] = (f32x4){0.f, 0.f, 0.f, 0.f};
}

// ----------------------------- sort kernels ---------------------------------
__global__ __launch_bounds__(256) void k_zeroI(int* cnt) {
  cnt[blockIdx.x * 256 + threadIdx.x] = 0;
}

__global__ __launch_bounds__(256) void k_hist(const int* r0, const int* r1,
                                              const int* r2, int* cnt) {
  const int t = blockIdx.z;
  const int* rcv = t == 0 ? r0 : (t == 1 ? r1 : r2);
  const int e = blockIdx.x * 256 + threadIdx.x;
  atomicAdd(&cnt[t * N_ELEC + rcv[e]], 1);
}

__global__ __launch_bounds__(256) void k_scan(const int* cnt, int* rowptr,
                                              int* cursor) {
  const int t = blockIdx.x, tid = threadIdx.x;
  __shared__ int part[256];
  const int* c = cnt + t * N_ELEC;
  int s = 0;
#pragma unroll
  for (int i = 0; i < 32; ++i) s += c[tid * 32 + i];
  part[tid] = s;
  __syncthreads();
  for (int off = 1; off < 256; off <<= 1) {
    int v = (tid >= off) ? part[tid - off] : 0;
    __syncthreads();
    part[tid] += v;
    __syncthreads();
  }
  int run = (tid == 0) ? 0 : part[tid - 1];
  int* rp = rowptr + t * RPS;
  int* cu = cursor + t * N_ELEC;
  for (int i = 0; i < 32; ++i) {
    rp[tid * 32 + i] = run;
    cu[tid * 32 + i] = run;
    run += c[tid * 32 + i];
  }
  if (tid == 255) rp[N_ELEC] = run;  // = NEDGE
}

__global__ __launch_bounds__(256) void k_place(const int* r0, const int* r1,
                                               const int* r2, const int* s0,
                                               const int* s1, const int* s2,
                                               int* cursor, int* perm,
                                               int* snd_s) {
  const int t = blockIdx.z;
  const int* rcv = t == 0 ? r0 : (t == 1 ? r1 : r2);
  const int* snd = t == 0 ? s0 : (t == 1 ? s1 : s2);
  const int e = blockIdx.x * 256 + threadIdx.x;
  const int pos = atomicAdd(&cursor[t * N_ELEC + rcv[e]], 1);
  perm[t * NEDGE + pos] = e;
  snd_s[t * NEDGE + pos] = snd[e];
}

// ------------------ prep: f32 weights -> transposed bf16 --------------------
// hwT [KER][EMB], w1T [3][MID][DF], w2T [3][KER][MID], gT [EMB][3*KER]
__global__ __launch_bounds__(256) void k_prep(
    const float* h_w, const float* w1s, const float* w1a, const float* w1n,
    const float* w2s, const float* w2a, const float* w2n, const float* gs,
    const float* ga, const float* gn, u16* hwT, u16* w1T, u16* w2T, u16* gT) {
  int i = blockIdx.x * 256 + threadIdx.x;
  if (i < 65536) {
    int n = i >> 8, k = i & 255;
    hwT[i] = f2bf(h_w[k * 256 + n]);
    return;
  }
  int j = i - 65536;
  if (j < 24576) {
    int t = j >> 13, jj = j & 8191, n = jj >> 6, k = jj & 63;
    const float* w1 = t == 0 ? w1s : (t == 1 ? w1a : w1n);
    w1T[j] = f2bf(w1[k * 128 + n]);
    return;
  }
  j -= 24576;
  if (j < 98304) {
    int t = j >> 15, jj = j & 32767, n = jj >> 7, k = jj & 127;
    const float* w2 = t == 0 ? w2s : (t == 1 ? w2a : w2n);
    w2T[j] = f2bf(w2[k * 256 + n]);
    return;
  }
  j -= 98304;
  if (j < 196608) {
    int n = j / 768, q = j % 768, t = q >> 8, k = q & 255;
    const float* g = t == 0 ? gs : (t == 1 ? ga : gn);
    gT[j] = f2bf(g[k * 256 + n]);
  }
}

// --------------------------- he = electrons @ h_w ---------------------------
__global__ __launch_bounds__(256) void k_he(const float* elec, const u16* hwT,
                                            u16* he) {
  __shared__ char As[8192], Bs[8192];
  f32x4 acc[4][4];
  zero_acc(acc);
  const int m0 = blockIdx.x * 128, n0 = blockIdx.y * 128;
  gemm_core<true>(nullptr, 0, elec + (long)m0 * 256, 256,
                  (const char*)hwT + (long)n0 * 512, 512, 256, As, Bs, acc,
                  threadIdx.x);
  const int l = threadIdx.x & 63, lane15 = l & 15, quad = l >> 4,
            wv = threadIdx.x >> 6;
  const int mw = (wv >> 1) * 64, nw = (wv & 1) * 64;
#pragma unroll
  for (int mi = 0; mi < 4; ++mi)
#pragma unroll
    for (int r = 0; r < 4; ++r) {
      const int row = m0 + mw + mi * 16 + quad * 4 + r;
#pragma unroll
      for (int ni = 0; ni < 4; ++ni) {
        const int col = n0 + nw + ni * 16 + lane15;
        he[row * 256 + col] = f2bf(acc[mi][ni][r]);
      }
    }
}

// ---- midact[pos] = SSP(dist[perm[pos]] @ w1 + b1), receiver-sorted order ---
// Dedicated kernel: A gathered f32->bf16 into LDS (one barrier, float4 loads,
// perm loaded once); B (w1T, 16 KB, L2-hot) read directly into fragments.
__global__ __launch_bounds__(256) void k_mlp1(
    const float* d0, const float* d1, const float* d2, const float* b0,
    const float* b1p, const float* b2, const u16* w1T, const int* perm,
    u16* midact) {
  __shared__ char As[2][8192];  // K halves: [128][32] bf16, 64 B rows
  const int t = blockIdx.z;
  const float* dist = t == 0 ? d0 : (t == 1 ? d1 : d2);
  const float* bias = t == 0 ? b0 : (t == 1 ? b1p : b2);
  const u16* w1t = w1T + t * 8192;  // [128][64]
  const int m0 = blockIdx.x * 128;
  const int tid = threadIdx.x;

  // stage A: 128 gathered rows x 64 cols, float4 chunks, convert to bf16
  int rows[4];
  const int* pm = perm + t * NEDGE + m0;
#pragma unroll
  for (int s = 0; s < 4; ++s) rows[s] = pm[(s * 256 + tid) >> 3];
#pragma unroll
  for (int j = 0; j < 2; ++j)
#pragma unroll
    for (int s = 0; s < 4; ++s) {
      const int idx = s * 256 + tid, row = idx >> 3, ch = idx & 7;
      const float4 v =
          *(const float4*)(dist + (long)rows[s] * 64 + j * 32 + ch * 4);
      uint2 p;
      p.x = pkbf(v.x, v.y);
      p.y = pkbf(v.z, v.w);
      *(uint2*)(As[j] + row * 64 + ch * 8) = p;
    }
  __syncthreads();

  const int l = tid & 63, lane15 = l & 15, quad = l >> 4, wv = tid >> 6;
  const int mw = (wv >> 1) * 64, nw = (wv & 1) * 64;
  f32x4 acc[4][4];
  zero_acc(acc);
#pragma unroll
  for (int j = 0; j < 2; ++j) {
    short8 af[4], bf[4];
#pragma unroll
    for (int i = 0; i < 4; ++i) {
      af[i] = *(const short8*)(As[j] + (mw + i * 16 + lane15) * 64 + quad * 16);
      bf[i] = *(const short8*)(w1t + (nw + i * 16 + lane15) * 64 + j * 32 +
                               quad * 8);
    }
#pragma unroll
    for (int mi = 0; mi < 4; ++mi)
#pragma unroll
      for (int ni = 0; ni < 4; ++ni)
        acc[mi][ni] = __builtin_amdgcn_mfma_f32_16x16x32_bf16(
            af[mi], bf[ni], acc[mi][ni], 0, 0, 0);
  }

  u16* mout = midact + (size_t)t * ((size_t)NEDGE * MID);
#pragma unroll
  for (int mi = 0; mi < 4; ++mi)
#pragma unroll
    for (int r = 0; r < 4; ++r) {
      const int row = m0 + mw + mi * 16 + quad * 4 + r;  // sorted position
#pragma unroll
      for (int ni = 0; ni < 4; ++ni) {
        const int col = nw + ni * 16 + lane15;
        const float x = acc[mi][ni][r] + bias[col];
        mout[(size_t)row * MID + col] = f2bf(ssp_fast(x));
      }
    }
}

// ------ weh[pos] = (midact @ w2)[pos] * src[snd_s[pos]]  (plain stores) -----
__global__ __launch_bounds__(256) void k_weh(const u16* midact_t,
                                             const u16* w2T_t, const u16* he,
                                             const float* nucf,
                                             const int* snd_s_t, int is_nuc,
                                             u16* weh) {
  __shared__ char As[8192], Bs[8192];
  f32x4 acc[4][4];
  zero_acc(acc);
  const int m0 = blockIdx.x * 128, n0 = blockIdx.y * 128;
  gemm_core<false>((const char*)midact_t + (long)m0 * 256, 256, nullptr, 0,
                   (const char*)w2T_t + (long)n0 * 256, 256, 128, As, Bs, acc,
                   threadIdx.x);
  const int l = threadIdx.x & 63, lane15 = l & 15, quad = l >> 4,
            wv = threadIdx.x >> 6;
  const int mw = (wv >> 1) * 64, nw = (wv & 1) * 64;
#pragma unroll
  for (int mi = 0; mi < 4; ++mi)
#pragma unroll
    for (int r = 0; r < 4; ++r) {
      const int e = m0 + mw + mi * 16 + quad * 4 + r;  // sorted position
      const int se = snd_s_t[e];
      u16* wrow = weh + (size_t)e * 256;
#pragma unroll
      for (int ni = 0; ni < 4; ++ni) {
        const int c = n0 + nw + ni * 16 + lane15;
        const float s = is_nuc ? nucf[(size_t)se * 256 + c]
                               : bf2f(he[(size_t)se * 256 + c]);
        wrow[c] = f2bf(acc[mi][ni][r] * s);
      }
    }
}

// --- zbf[r][t*256+:] = segment sum of weh rows; uint4 (8 bf16) per thread ---
__global__ __launch_bounds__(256) void k_gather(const u16* weh,
                                                const int* rowptr_t, int t,
                                                u16* zbf) {
  const int tid = threadIdx.x;
  const int r = blockIdx.x * 8 + (tid >> 5);  // 8 receivers/block
  const int c8 = (tid & 31) * 8;              // 8 cols per thread
  const int start = rowptr_t[r], end = rowptr_t[r + 1];
  float a[8] = {0.f, 0.f, 0.f, 0.f, 0.f, 0.f, 0.f, 0.f};
  for (int i = start; i < end; ++i) {
    const uint4 p = *(const uint4*)(weh + (size_t)i * 256 + c8);
    const unsigned w[4] = {p.x, p.y, p.z, p.w};
#pragma unroll
    for (int q = 0; q < 4; ++q) {
      a[q * 2] += __uint_as_float(w[q] << 16);
      a[q * 2 + 1] += __uint_as_float(w[q] & 0xffff0000u);
    }
  }
  uint4 o;
  o.x = pkbf(a[0], a[1]);
  o.y = pkbf(a[2], a[3]);
  o.z = pkbf(a[4], a[5]);
  o.w = pkbf(a[6], a[7]);
  *(uint4*)(zbf + (size_t)r * 768 + t * 256 + c8) = o;
}

// ------------- out = electrons_f32 + zbf[8192,768] @ gT^T  (f32) ------------
__global__ __launch_bounds__(256) void k_final(const u16* zbf, const u16* gT,
                                               const float* elec, float* out) {
  __shared__ char As[8192], Bs[8192];
  f32x4 acc[4][4];
  zero_acc(acc);
  const int m0 = blockIdx.x * 128, n0 = blockIdx.y * 128;
  gemm_core<false>((const char*)zbf + (long)m0 * 1536, 1536, nullptr, 0,
                   (const char*)gT + (long)n0 * 1536, 1536, 768, As, Bs, acc,
                   threadIdx.x);
  const int l = threadIdx.x & 63, lane15 = l & 15, quad = l >> 4,
            wv = threadIdx.x >> 6;
  const int mw = (wv >> 1) * 64, nw = (wv & 1) * 64;
#pragma unroll
  for (int mi = 0; mi < 4; ++mi)
#pragma unroll
    for (int r = 0; r < 4; ++r) {
      const int row = m0 + mw + mi * 16 + quad * 4 + r;
#pragma unroll
      for (int ni = 0; ni < 4; ++ni) {
        const int col = n0 + nw + ni * 16 + lane15;
        out[row * 256 + col] = acc[mi][ni][r] + elec[row * 256 + col];
      }
    }
}

// ---------------------------------------------------------------------------
extern "C" void kernel_launch(void* const* d_in, const int* in_sizes, int n_in,
                              void* d_out, int out_size, void* d_ws,
                              size_t ws_size, hipStream_t stream) {
  int I_dist[3], I_w1[3], I_b1[3], I_w2[3], I_g[3], I_hw;
  if (in_sizes[3] == 64 * 128) {  // setup_inputs() dict order
    for (int t = 0; t < 3; ++t) {
      I_dist[t] = 2 + t * 5 + 0;
      I_w1[t] = 2 + t * 5 + 1;
      I_b1[t] = 2 + t * 5 + 2;
      I_w2[t] = 2 + t * 5 + 3;
      I_g[t] = 2 + t * 5 + 4;
    }
    I_hw = 17;
  } else {  // reference signature order
    I_dist[0] = 2; I_dist[1] = 3; I_dist[2] = 4;
    I_w1[0] = 5;  I_b1[0] = 6;  I_w2[0] = 7;
    I_w1[1] = 8;  I_b1[1] = 9;  I_w2[1] = 10;
    I_w1[2] = 11; I_b1[2] = 12; I_w2[2] = 13;
    I_g[0] = 14; I_g[1] = 15; I_g[2] = 16;
    I_hw = 17;
  }
  const int I_snd[3] = {18, 19, 20};
  const int I_rcv[3] = {21, 22, 23};

  char* ws = (char*)d_ws;
  // workspace layout (bytes). Total ~189 MB.
  u16* he = (u16*)(ws + 0);                   //   4,194,304
  u16* hwT = (u16*)(ws + 4194304);            //     131,072
  u16* w1T = (u16*)(ws + 4325376);            //      49,152
  u16* w2T = (u16*)(ws + 4374528);            //     196,608
  u16* gT = (u16*)(ws + 4571136);             //     393,216
  u16* midact = (u16*)(ws + 4964352);         // 100,663,296
  u16* weh = (u16*)(ws + 105627648);          //  67,108,864 (per-type, reused)
  u16* zbf = (u16*)(ws + 172736512);          //  12,582,912
  int* cnt = (int*)(ws + 185319424);          //      98,304
  int* rowptr = (int*)(ws + 185417728);       //      99,072
  int* cursor = (int*)(ws + 185516800);       //      98,304
  int* perm = (int*)(ws + 185615104);         //   1,572,864
  int* snd_s = (int*)(ws + 187187968);        //   1,572,864

  const float* elec = (const float*)d_in[0];
  const float* nuc = (const float*)d_in[1];
  const int* s0 = (const int*)d_in[I_snd[0]];
  const int* s1 = (const int*)d_in[I_snd[1]];
  const int* s2 = (const int*)d_in[I_snd[2]];
  const int* r0 = (const int*)d_in[I_rcv[0]];
  const int* r1 = (const int*)d_in[I_rcv[1]];
  const int* r2 = (const int*)d_in[I_rcv[2]];

  // --- counting sort by receiver, per type ---
  k_zeroI<<<3 * N_ELEC / 256, 256, 0, stream>>>(cnt);
  k_hist<<<dim3(NEDGE / 256, 1, 3), 256, 0, stream>>>(r0, r1, r2, cnt);
  k_scan<<<3, 256, 0, stream>>>(cnt, rowptr, cursor);
  k_place<<<dim3(NEDGE / 256, 1, 3), 256, 0, stream>>>(r0, r1, r2, s0, s1, s2,
                                                       cursor, perm, snd_s);

  k_prep<<<1504, 256, 0, stream>>>(
      (const float*)d_in[I_hw], (const float*)d_in[I_w1[0]],
      (const float*)d_in[I_w1[1]], (const float*)d_in[I_w1[2]],
      (const float*)d_in[I_w2[0]], (const float*)d_in[I_w2[1]],
      (const float*)d_in[I_w2[2]], (const float*)d_in[I_g[0]],
      (const float*)d_in[I_g[1]], (const float*)d_in[I_g[2]], hwT, w1T, w2T,
      gT);

  k_he<<<dim3(N_ELEC / 128, 2), 256, 0, stream>>>(elec, hwT, he);

  k_mlp1<<<dim3(NEDGE / 128, 1, 3), 256, 0, stream>>>(
      (const float*)d_in[I_dist[0]], (const float*)d_in[I_dist[1]],
      (const float*)d_in[I_dist[2]], (const float*)d_in[I_b1[0]],
      (const float*)d_in[I_b1[1]], (const float*)d_in[I_b1[2]], w1T, perm,
      midact);

  for (int t = 0; t < 3; ++t) {
    k_weh<<<dim3(NEDGE / 128, 2), 256, 0, stream>>>(
        midact + (size_t)t * ((size_t)NEDGE * MID), w2T + t * 32768, he, nuc,
        snd_s + t * NEDGE, t == 2 ? 1 : 0, weh);
    k_gather<<<N_ELEC / 8, 256, 0, stream>>>(weh, rowptr + t * RPS, t, zbf);
  }

  k_final<<<dim3(N_ELEC / 128, 2), 256, 0, stream>>>(zbf, gT, elec,
                                                     (float*)d_out);
}

// Round 5
// 464.843 us; speedup vs baseline: 1.6509x; 1.2185x over previous
//
#include <hip/hip_runtime.h>
#include <stdint.h>

// ---------------------------------------------------------------------------
// SchNetLayer on MI355X (gfx950).
// I/O: float tensors f32, indices int32. Internal: bf16 MFMA.
//
// R2: atomic scatter (100M f32 atomics) = atomic-rate bound -> counting sort.
// R3: k_mlp1 251us @75% VALUBusy = libm softplus -> native v_exp/v_log.
// R4: k_weh 233us latency-bound (scalar he gathers + 402 MB weh round-trip)
//     -> R5: fuse k_weh+k_gather into k_wz: LDS-staged he rows (coalesced),
//     in-place multiply, per-tile segmented reduce, few f32 atomics into z.
//
// Pipeline:
//   sort:  k_zeroI, k_hist, k_scan, k_place  (counting sort by receiver)
//   k_zero : z = 0                            [8192,768] f32
//   k_prep : cast+transpose weights -> bf16 ws
//   k_he   : he = bf16(electrons) @ h_w       [8192,256] bf16
//   k_mlp1 : midact[pos] = SSP(bf16(dist[perm[pos]]) @ w1 + b1)  (sorted)
//   k_wz   : per tile: we=(midact@w2); weh=we*src[snd]; segment-sum by
//            receiver run; atomicAdd partials into z  (grid z = 3 types)
//   k_final: out = electrons + bf16(z) @ g_catT   f32 out
// ---------------------------------------------------------------------------

#define N_ELEC 8192
#define N_NUC  512
#define EMB    256
#define KER    256
#define DF     64
#define MID    128
#define NEDGE  131072
#define RPS    8256   // rowptr per-type stride (ints)
#define CSTR   272    // k_wz LDS row stride in bytes (136 u16: pad kills 4-way)

using u16 = unsigned short;
typedef short short8 __attribute__((ext_vector_type(8)));
typedef float f32x4 __attribute__((ext_vector_type(4)));

__device__ __forceinline__ float bf2f(u16 h) {
  return __uint_as_float(((unsigned)h) << 16);
}
__device__ __forceinline__ u16 f2bf(float f) {
  unsigned u = __float_as_uint(f);
  return (u16)((u + 0x7FFFu + ((u >> 16) & 1u)) >> 16);  // RNE
}
__device__ __forceinline__ unsigned pkbf(float a, float b) {
  return ((unsigned)f2bf(b) << 16) | (unsigned)f2bf(a);
}
// fast shifted softplus: log(0.5 e^x + 0.5), stable, native v_exp/v_log.
__device__ __forceinline__ float ssp_fast(float x) {
  const float e = __expf(-fabsf(x));
  return fmaxf(x, 0.f) + __logf(fmaf(0.5f, e, 0.5f));
}

// Stage a 128x32 bf16 tile (row-major, row stride bytes) into an 8 KB LDS
// buffer [128][32] bf16 (64 B rows) via global_load_lds (width 16).
__device__ __forceinline__ void stage_tile(const char* g0, long stride,
                                           char* lds, int tid) {
  const int l = tid & 63, w = tid >> 6;
#pragma unroll
  for (int c = 0; c < 2; ++c) {
    const int r = c * 64 + w * 16 + (l >> 2);
    const int cb = (l & 3) * 16;
    const char* g = g0 + (long)r * stride + cb;
    char* dst = lds + c * 4096 + w * 1024;  // wave-uniform base
    __builtin_amdgcn_global_load_lds(
        (const __attribute__((address_space(1))) unsigned*)g,
        (__attribute__((address_space(3))) unsigned*)dst, 16, 0, 0);
  }
}

// Stage a 128x32 tile of an f32 matrix into [128][32]-bf16 LDS.
__device__ __forceinline__ void stage_f32(const float* g0, int stride_e,
                                          int kt, char* lds, int tid) {
#pragma unroll
  for (int k = 0; k < 8; ++k) {
    const int idx2 = k * 256 + tid;
    const int row = idx2 >> 4, cp = idx2 & 15;
    const float2 v = *(const float2*)(g0 + (long)row * stride_e + kt + cp * 2);
    *(unsigned*)(lds + row * 64 + cp * 4) = pkbf(v.x, v.y);
  }
}

// 128x128 tile GEMM: C = A[128,K] * Bt[128,K]^T, bf16 MFMA 16x16x32,
// 4 waves in 2x2 quadrants, 4x4 fragments each.
template <bool A_F32>
__device__ __forceinline__ void gemm_core(const char* A0, long as_bytes,
                                          const float* Af, int as_elems,
                                          const char* B0, long bs, int K,
                                          char* As, char* Bs, f32x4 acc[4][4],
                                          int tid) {
  const int l = tid & 63, lane15 = l & 15, quad = l >> 4, wv = tid >> 6;
  const int mw = (wv >> 1) * 64, nw = (wv & 1) * 64;
  for (int kt = 0; kt < K; kt += 32) {
    if (A_F32)
      stage_f32(Af, as_elems, kt, As, tid);
    else
      stage_tile(A0 + (long)kt * 2, as_bytes, As, tid);
    stage_tile(B0 + (long)kt * 2, bs, Bs, tid);
    __syncthreads();
    short8 af[4], bf[4];
#pragma unroll
    for (int i = 0; i < 4; ++i) {
      af[i] = *(const short8*)(As + (mw + i * 16 + lane15) * 64 + quad * 16);
      bf[i] = *(const short8*)(Bs + (nw + i * 16 + lane15) * 64 + quad * 16);
    }
#pragma unroll
    for (int mi = 0; mi < 4; ++mi)
#pragma unroll
      for (int ni = 0; ni < 4; ++ni)
        acc[mi][ni] = __builtin_amdgcn_mfma_f32_16x16x32_bf16(
            af[mi], bf[ni], acc[mi][ni], 0, 0, 0);
    __syncthreads();
  }
}

__device__ __forceinline__ void zero_acc(f32x4 acc[4][4]) {
#pragma unroll
  for (int i = 0; i < 4; ++i)
#pragma unroll
    for (int j = 0; j < 4; ++j) acc[i][j] = (f32x4){0.f, 0.f, 0.f, 0.f};
}

// ----------------------------- sort kernels ---------------------------------
__global__ __launch_bounds__(256) void k_zeroI(int* cnt) {
  cnt[blockIdx.x * 256 + threadIdx.x] = 0;
}

__global__ __launch_bounds__(256) void k_hist(const int* r0, const int* r1,
                                              const int* r2, int* cnt) {
  const int t = blockIdx.z;
  const int* rcv = t == 0 ? r0 : (t == 1 ? r1 : r2);
  const int e = blockIdx.x * 256 + threadIdx.x;
  atomicAdd(&cnt[t * N_ELEC + rcv[e]], 1);
}

__global__ __launch_bounds__(256) void k_scan(const int* cnt, int* rowptr,
                                              int* cursor) {
  const int t = blockIdx.x, tid = threadIdx.x;
  __shared__ int part[256];
  const int* c = cnt + t * N_ELEC;
  int s = 0;
#pragma unroll
  for (int i = 0; i < 32; ++i) s += c[tid * 32 + i];
  part[tid] = s;
  __syncthreads();
  for (int off = 1; off < 256; off <<= 1) {
    int v = (tid >= off) ? part[tid - off] : 0;
    __syncthreads();
    part[tid] += v;
    __syncthreads();
  }
  int run = (tid == 0) ? 0 : part[tid - 1];
  int* rp = rowptr + t * RPS;
  int* cu = cursor + t * N_ELEC;
  for (int i = 0; i < 32; ++i) {
    rp[tid * 32 + i] = run;
    cu[tid * 32 + i] = run;
    run += c[tid * 32 + i];
  }
  if (tid == 255) rp[N_ELEC] = run;  // = NEDGE
}

__global__ __launch_bounds__(256) void k_place(const int* r0, const int* r1,
                                               const int* r2, const int* s0,
                                               const int* s1, const int* s2,
                                               int* cursor, int* perm,
                                               int* snd_s, int* rcv_s) {
  const int t = blockIdx.z;
  const int* rcv = t == 0 ? r0 : (t == 1 ? r1 : r2);
  const int* snd = t == 0 ? s0 : (t == 1 ? s1 : s2);
  const int e = blockIdx.x * 256 + threadIdx.x;
  const int rr = rcv[e];
  const int pos = atomicAdd(&cursor[t * N_ELEC + rr], 1);
  perm[t * NEDGE + pos] = e;
  snd_s[t * NEDGE + pos] = snd[e];
  rcv_s[t * NEDGE + pos] = rr;
}

// ------------------------------- z = 0 --------------------------------------
__global__ __launch_bounds__(256) void k_zero(float4* z) {
  z[blockIdx.x * 256 + threadIdx.x] = (float4){0.f, 0.f, 0.f, 0.f};
}

// ------------------ prep: f32 weights -> transposed bf16 --------------------
// hwT [KER][EMB], w1T [3][MID][DF], w2T [3][KER][MID], gT [EMB][3*KER]
__global__ __launch_bounds__(256) void k_prep(
    const float* h_w, const float* w1s, const float* w1a, const float* w1n,
    const float* w2s, const float* w2a, const float* w2n, const float* gs,
    const float* ga, const float* gn, u16* hwT, u16* w1T, u16* w2T, u16* gT) {
  int i = blockIdx.x * 256 + threadIdx.x;
  if (i < 65536) {
    int n = i >> 8, k = i & 255;
    hwT[i] = f2bf(h_w[k * 256 + n]);
    return;
  }
  int j = i - 65536;
  if (j < 24576) {
    int t = j >> 13, jj = j & 8191, n = jj >> 6, k = jj & 63;
    const float* w1 = t == 0 ? w1s : (t == 1 ? w1a : w1n);
    w1T[j] = f2bf(w1[k * 128 + n]);
    return;
  }
  j -= 24576;
  if (j < 98304) {
    int t = j >> 15, jj = j & 32767, n = jj >> 7, k = jj & 127;
    const float* w2 = t == 0 ? w2s : (t == 1 ? w2a : w2n);
    w2T[j] = f2bf(w2[k * 256 + n]);
    return;
  }
  j -= 98304;
  if (j < 196608) {
    int n = j / 768, q = j % 768, t = q >> 8, k = q & 255;
    const float* g = t == 0 ? gs : (t == 1 ? ga : gn);
    gT[j] = f2bf(g[k * 256 + n]);
  }
}

// --------------------------- he = electrons @ h_w ---------------------------
__global__ __launch_bounds__(256) void k_he(const float* elec, const u16* hwT,
                                            u16* he) {
  __shared__ char As[8192], Bs[8192];
  f32x4 acc[4][4];
  zero_acc(acc);
  const int m0 = blockIdx.x * 128, n0 = blockIdx.y * 128;
  gemm_core<true>(nullptr, 0, elec + (long)m0 * 256, 256,
                  (const char*)hwT + (long)n0 * 512, 512, 256, As, Bs, acc,
                  threadIdx.x);
  const int l = threadIdx.x & 63, lane15 = l & 15, quad = l >> 4,
            wv = threadIdx.x >> 6;
  const int mw = (wv >> 1) * 64, nw = (wv & 1) * 64;
#pragma unroll
  for (int mi = 0; mi < 4; ++mi)
#pragma unroll
    for (int r = 0; r < 4; ++r) {
      const int row = m0 + mw + mi * 16 + quad * 4 + r;
#pragma unroll
      for (int ni = 0; ni < 4; ++ni) {
        const int col = n0 + nw + ni * 16 + lane15;
        he[row * 256 + col] = f2bf(acc[mi][ni][r]);
      }
    }
}

// ---- midact[pos] = SSP(dist[perm[pos]] @ w1 + b1), receiver-sorted order ---
__global__ __launch_bounds__(256) void k_mlp1(
    const float* d0, const float* d1, const float* d2, const float* b0,
    const float* b1p, const float* b2, const u16* w1T, const int* perm,
    u16* midact) {
  __shared__ char As[2][8192];  // K halves: [128][32] bf16, 64 B rows
  const int t = blockIdx.z;
  const float* dist = t == 0 ? d0 : (t == 1 ? d1 : d2);
  const float* bias = t == 0 ? b0 : (t == 1 ? b1p : b2);
  const u16* w1t = w1T + t * 8192;  // [128][64]
  const int m0 = blockIdx.x * 128;
  const int tid = threadIdx.x;

  int rows[4];
  const int* pm = perm + t * NEDGE + m0;
#pragma unroll
  for (int s = 0; s < 4; ++s) rows[s] = pm[(s * 256 + tid) >> 3];
#pragma unroll
  for (int j = 0; j < 2; ++j)
#pragma unroll
    for (int s = 0; s < 4; ++s) {
      const int idx = s * 256 + tid, row = idx >> 3, ch = idx & 7;
      const float4 v =
          *(const float4*)(dist + (long)rows[s] * 64 + j * 32 + ch * 4);
      uint2 p;
      p.x = pkbf(v.x, v.y);
      p.y = pkbf(v.z, v.w);
      *(uint2*)(As[j] + row * 64 + ch * 8) = p;
    }
  __syncthreads();

  const int l = tid & 63, lane15 = l & 15, quad = l >> 4, wv = tid >> 6;
  const int mw = (wv >> 1) * 64, nw = (wv & 1) * 64;
  f32x4 acc[4][4];
  zero_acc(acc);
#pragma unroll
  for (int j = 0; j < 2; ++j) {
    short8 af[4], bf[4];
#pragma unroll
    for (int i = 0; i < 4; ++i) {
      af[i] = *(const short8*)(As[j] + (mw + i * 16 + lane15) * 64 + quad * 16);
      bf[i] = *(const short8*)(w1t + (nw + i * 16 + lane15) * 64 + j * 32 +
                               quad * 8);
    }
#pragma unroll
    for (int mi = 0; mi < 4; ++mi)
#pragma unroll
      for (int ni = 0; ni < 4; ++ni)
        acc[mi][ni] = __builtin_amdgcn_mfma_f32_16x16x32_bf16(
            af[mi], bf[ni], acc[mi][ni], 0, 0, 0);
  }

  u16* mout = midact + (size_t)t * ((size_t)NEDGE * MID);
#pragma unroll
  for (int mi = 0; mi < 4; ++mi)
#pragma unroll
    for (int r = 0; r < 4; ++r) {
      const int row = m0 + mw + mi * 16 + quad * 4 + r;
#pragma unroll
      for (int ni = 0; ni < 4; ++ni) {
        const int col = nw + ni * 16 + lane15;
        const float x = acc[mi][ni][r] + bias[col];
        mout[(size_t)row * MID + col] = f2bf(ssp_fast(x));
      }
    }
}

// ------ fused: we=(midact@w2); weh=we*src[snd]; segment-sum -> z atomics ----
// Block = 128 sorted edges x 128 ker cols. Phases:
//  0: load snd/rcv for tile into LDS meta
//  1: GEMM (As/Bs in smem[0:16K))
//  2: stage src rows (he bf16 / nuc f32->bf16) into HeC (coalesced dwordx4)
//  3: in-place multiply HeC[row][col] *= acc  (unique owner per cell)
//  4: per-wave segmented reduce over 32-row strips -> f32 atomics into z
__global__ __launch_bounds__(256) void k_wz(const u16* midact, const u16* w2T,
                                            const u16* he, const float* nucf,
                                            const int* snd_s, const int* rcv_s,
                                            float* z) {
  __shared__ char smem[128 * CSTR + 1024];
  int* snd_l = (int*)(smem + 128 * CSTR);
  int* rcv_l = snd_l + 128;

  const int t = blockIdx.z;
  const int m0 = blockIdx.x * 128, n0 = blockIdx.y * 128;
  const int tid = threadIdx.x;
  const bool is_nuc = (t == 2);
  const u16* midact_t = midact + (size_t)t * ((size_t)NEDGE * MID);
  const u16* w2T_t = w2T + t * 32768;

  // phase 0: tile meta (visibility covered by gemm_core's barriers)
  if (tid < 128)
    snd_l[tid] = snd_s[t * NEDGE + m0 + tid];
  else
    rcv_l[tid - 128] = rcv_s[t * NEDGE + m0 + tid - 128];

  // phase 1: GEMM
  f32x4 acc[4][4];
  zero_acc(acc);
  gemm_core<false>((const char*)midact_t + (long)m0 * 256, 256, nullptr, 0,
                   (const char*)w2T_t + (long)n0 * 256, 256, 128, smem,
                   smem + 8192, acc, tid);

  // phase 2: stage 128 src rows (cols n0..n0+128) into HeC
  u16* HeC = (u16*)smem;
  if (!is_nuc) {
#pragma unroll
    for (int c = 0; c < 8; ++c) {
      const int chunk = c * 256 + tid;  // 2048 x 16B
      const int row = chunk >> 4, off = chunk & 15;
      const uint4 v = *(const uint4*)((const char*)he +
                                      (size_t)snd_l[row] * 512 + n0 * 2 +
                                      off * 16);
      *(uint4*)((char*)HeC + row * CSTR + off * 16) = v;
    }
  } else {
#pragma unroll
    for (int c = 0; c < 8; ++c) {
      const int chunk = c * 256 + tid;
      const int row = chunk >> 4, off = chunk & 15;
      const char* src =
          (const char*)nucf + (size_t)snd_l[row] * 1024 + n0 * 4 + off * 32;
      const float4 a = *(const float4*)src;
      const float4 b = *(const float4*)(src + 16);
      uint4 p;
      p.x = pkbf(a.x, a.y);
      p.y = pkbf(a.z, a.w);
      p.z = pkbf(b.x, b.y);
      p.w = pkbf(b.z, b.w);
      *(uint4*)((char*)HeC + row * CSTR + off * 16) = p;
    }
  }
  __syncthreads();

  // phase 3: in-place multiply (each cell owned by exactly one lane)
  const int l = tid & 63, lane15 = l & 15, quad = l >> 4, wv = tid >> 6;
  const int mw = (wv >> 1) * 64, nw = (wv & 1) * 64;
#pragma unroll
  for (int mi = 0; mi < 4; ++mi)
#pragma unroll
    for (int r = 0; r < 4; ++r) {
      const int row = mw + mi * 16 + quad * 4 + r;
#pragma unroll
      for (int ni = 0; ni < 4; ++ni) {
        const int col = nw + ni * 16 + lane15;
        u16* p = (u16*)((char*)HeC + row * CSTR) + col;
        *p = f2bf(acc[mi][ni][r] * bf2f(*p));
      }
    }
  __syncthreads();

  // phase 4: segmented reduce. Wave wv owns rows [wv*32, wv*32+32); lane owns
  // col pair. Strip edges forced as segment boundaries (extra atomics only).
  {
    const int cp = l;  // 0..63 col pairs (128 cols)
    const int rbeg = wv * 32, rend = rbeg + 32;
    float a0 = 0.f, a1 = 0.f;
    int cur = rcv_l[rbeg];
    for (int row = rbeg; row < rend; ++row) {
      const unsigned p = *(const unsigned*)((char*)HeC + row * CSTR + cp * 4);
      a0 += __uint_as_float(p << 16);
      a1 += __uint_as_float(p & 0xffff0000u);
      const int nxt = (row + 1 < rend) ? rcv_l[row + 1] : -1;
      if (nxt != cur) {
        float* zp = z + (size_t)cur * 768 + t * 256 + n0 + cp * 2;
        unsafeAtomicAdd(zp, a0);
        unsafeAtomicAdd(zp + 1, a1);
        a0 = a1 = 0.f;
        cur = nxt;
      }
    }
  }
}

// ---------- out = electrons_f32 + bf16(z)[8192,768] @ gT^T  (f32) -----------
__global__ __launch_bounds__(256) void k_final(const float* z, const u16* gT,
                                               const float* elec, float* out) {
  __shared__ char As[8192], Bs[8192];
  f32x4 acc[4][4];
  zero_acc(acc);
  const int m0 = blockIdx.x * 128, n0 = blockIdx.y * 128;
  gemm_core<true>(nullptr, 0, z + (long)m0 * 768, 768,
                  (const char*)gT + (long)n0 * 1536, 1536, 768, As, Bs, acc,
                  threadIdx.x);
  const int l = threadIdx.x & 63, lane15 = l & 15, quad = l >> 4,
            wv = threadIdx.x >> 6;
  const int mw = (wv >> 1) * 64, nw = (wv & 1) * 64;
#pragma unroll
  for (int mi = 0; mi < 4; ++mi)
#pragma unroll
    for (int r = 0; r < 4; ++r) {
      const int row = m0 + mw + mi * 16 + quad * 4 + r;
#pragma unroll
      for (int ni = 0; ni < 4; ++ni) {
        const int col = n0 + nw + ni * 16 + lane15;
        out[row * 256 + col] = acc[mi][ni][r] + elec[row * 256 + col];
      }
    }
}

// ---------------------------------------------------------------------------
extern "C" void kernel_launch(void* const* d_in, const int* in_sizes, int n_in,
                              void* d_out, int out_size, void* d_ws,
                              size_t ws_size, hipStream_t stream) {
  int I_dist[3], I_w1[3], I_b1[3], I_w2[3], I_g[3], I_hw;
  if (in_sizes[3] == 64 * 128) {  // setup_inputs() dict order
    for (int t = 0; t < 3; ++t) {
      I_dist[t] = 2 + t * 5 + 0;
      I_w1[t] = 2 + t * 5 + 1;
      I_b1[t] = 2 + t * 5 + 2;
      I_w2[t] = 2 + t * 5 + 3;
      I_g[t] = 2 + t * 5 + 4;
    }
    I_hw = 17;
  } else {  // reference signature order
    I_dist[0] = 2; I_dist[1] = 3; I_dist[2] = 4;
    I_w1[0] = 5;  I_b1[0] = 6;  I_w2[0] = 7;
    I_w1[1] = 8;  I_b1[1] = 9;  I_w2[1] = 10;
    I_w1[2] = 11; I_b1[2] = 12; I_w2[2] = 13;
    I_g[0] = 14; I_g[1] = 15; I_g[2] = 16;
    I_hw = 17;
  }
  const int I_snd[3] = {18, 19, 20};
  const int I_rcv[3] = {21, 22, 23};

  char* ws = (char*)d_ws;
  // workspace layout (bytes). Total ~136 MB.
  u16* he = (u16*)(ws + 0);               //   4,194,304
  u16* hwT = (u16*)(ws + 4194304);        //     131,072
  u16* w1T = (u16*)(ws + 4325376);        //      49,152
  u16* w2T = (u16*)(ws + 4374528);        //     196,608
  u16* gT = (u16*)(ws + 4571136);         //     393,216
  u16* midact = (u16*)(ws + 4964352);     // 100,663,296
  float* z = (float*)(ws + 105627648);    //  25,165,824
  int* cnt = (int*)(ws + 130793472);      //      98,304
  int* rowptr = (int*)(ws + 130891776);   //      99,072
  int* cursor = (int*)(ws + 130990848);   //      98,304
  int* perm = (int*)(ws + 131089152);     //   1,572,864
  int* snd_s = (int*)(ws + 132662016);    //   1,572,864
  int* rcv_s = (int*)(ws + 134234880);    //   1,572,864

  const float* elec = (const float*)d_in[0];
  const float* nuc = (const float*)d_in[1];
  const int* s0 = (const int*)d_in[I_snd[0]];
  const int* s1 = (const int*)d_in[I_snd[1]];
  const int* s2 = (const int*)d_in[I_snd[2]];
  const int* r0 = (const int*)d_in[I_rcv[0]];
  const int* r1 = (const int*)d_in[I_rcv[1]];
  const int* r2 = (const int*)d_in[I_rcv[2]];

  // --- counting sort by receiver, per type ---
  k_zeroI<<<3 * N_ELEC / 256, 256, 0, stream>>>(cnt);
  k_hist<<<dim3(NEDGE / 256, 1, 3), 256, 0, stream>>>(r0, r1, r2, cnt);
  k_scan<<<3, 256, 0, stream>>>(cnt, rowptr, cursor);
  k_place<<<dim3(NEDGE / 256, 1, 3), 256, 0, stream>>>(r0, r1, r2, s0, s1, s2,
                                                       cursor, perm, snd_s,
                                                       rcv_s);

  k_zero<<<(N_ELEC * 768 / 4) / 256, 256, 0, stream>>>((float4*)z);

  k_prep<<<1504, 256, 0, stream>>>(
      (const float*)d_in[I_hw], (const float*)d_in[I_w1[0]],
      (const float*)d_in[I_w1[1]], (const float*)d_in[I_w1[2]],
      (const float*)d_in[I_w2[0]], (const float*)d_in[I_w2[1]],
      (const float*)d_in[I_w2[2]], (const float*)d_in[I_g[0]],
      (const float*)d_in[I_g[1]], (const float*)d_in[I_g[2]], hwT, w1T, w2T,
      gT);

  k_he<<<dim3(N_ELEC / 128, 2), 256, 0, stream>>>(elec, hwT, he);

  k_mlp1<<<dim3(NEDGE / 128, 1, 3), 256, 0, stream>>>(
      (const float*)d_in[I_dist[0]], (const float*)d_in[I_dist[1]],
      (const float*)d_in[I_dist[2]], (const float*)d_in[I_b1[0]],
      (const float*)d_in[I_b1[1]], (const float*)d_in[I_b1[2]], w1T, perm,
      midact);

  k_wz<<<dim3(NEDGE / 128, 2, 3), 256, 0, stream>>>(midact, w2T, he, nuc,
                                                    snd_s, rcv_s, z);

  k_final<<<dim3(N_ELEC / 128, 2), 256, 0, stream>>>(z, gT, elec,
                                                     (float*)d_out);
}

// Round 6
// 436.106 us; speedup vs baseline: 1.7597x; 1.0659x over previous
//
#include <hip/hip_runtime.h>
#include <stdint.h>

// ---------------------------------------------------------------------------
// SchNetLayer on MI355X (gfx950).
// I/O: float tensors f32, indices int32. Internal: bf16 MFMA.
//
// R2: atomic scatter (100M f32 atomics) = atomic-rate bound -> counting sort.
// R3: k_mlp1 251us @75% VALUBusy = libm softplus -> native v_exp/v_log.
// R4: k_weh latency-bound (scalar he gathers + 402MB weh round-trip) -> fuse.
// R5: k_wz FETCH 132MB dominated by midact round-trip (k_mlp1 writes 100MB,
//     k_wz reads it back; tiles align exactly) -> R6 fuses MLP1 into k_edge:
//     dist->GEMM1->SSP->mid in LDS->GEMM2->multiply->segment-reduce->z.
//
// Pipeline:
//   k_zero2: z = 0, cnt = 0
//   sort:  k_hist, k_scan, k_place        (counting sort by receiver)
//   k_prep : cast+transpose weights -> bf16 ws
//   k_he   : he = bf16(electrons) @ h_w   [8192,256] bf16
//   k_edge : per 128-edge tile (sorted): mid=SSP(dist[perm]@w1+b1) in LDS;
//            for n0 in {0,128}: we=mid@w2; weh=we*src[snd]; segmented
//            reduce by receiver run -> f32 atomics into z   (grid z = type)
//   k_final: out = electrons + bf16(z) @ g_catT   f32 out
// ---------------------------------------------------------------------------

#define N_ELEC 8192
#define N_NUC  512
#define EMB    256
#define KER    256
#define DF     64
#define MID    128
#define NEDGE  131072
#define RPS    8256   // rowptr per-type stride (ints)
#define CSTR   272    // LDS row stride bytes for 128-col u16 tiles (+16 pad)

using u16 = unsigned short;
typedef short short8 __attribute__((ext_vector_type(8)));
typedef float f32x4 __attribute__((ext_vector_type(4)));

__device__ __forceinline__ float bf2f(u16 h) {
  return __uint_as_float(((unsigned)h) << 16);
}
__device__ __forceinline__ u16 f2bf(float f) {
  unsigned u = __float_as_uint(f);
  return (u16)((u + 0x7FFFu + ((u >> 16) & 1u)) >> 16);  // RNE
}
__device__ __forceinline__ unsigned pkbf(float a, float b) {
  return ((unsigned)f2bf(b) << 16) | (unsigned)f2bf(a);
}
// fast shifted softplus: log(0.5 e^x + 0.5), stable, native v_exp/v_log.
__device__ __forceinline__ float ssp_fast(float x) {
  const float e = __expf(-fabsf(x));
  return fmaxf(x, 0.f) + __logf(fmaf(0.5f, e, 0.5f));
}

// Stage a 128x32 bf16 tile (row-major, row stride bytes) into an 8 KB LDS
// buffer [128][32] bf16 (64 B rows) via global_load_lds (width 16).
__device__ __forceinline__ void stage_tile(const char* g0, long stride,
                                           char* lds, int tid) {
  const int l = tid & 63, w = tid >> 6;
#pragma unroll
  for (int c = 0; c < 2; ++c) {
    const int r = c * 64 + w * 16 + (l >> 2);
    const int cb = (l & 3) * 16;
    const char* g = g0 + (long)r * stride + cb;
    char* dst = lds + c * 4096 + w * 1024;  // wave-uniform base
    __builtin_amdgcn_global_load_lds(
        (const __attribute__((address_space(1))) unsigned*)g,
        (__attribute__((address_space(3))) unsigned*)dst, 16, 0, 0);
  }
}

// Stage a 128x32 tile of an f32 matrix into [128][32]-bf16 LDS.
__device__ __forceinline__ void stage_f32(const float* g0, int stride_e,
                                          int kt, char* lds, int tid) {
#pragma unroll
  for (int k = 0; k < 8; ++k) {
    const int idx2 = k * 256 + tid;
    const int row = idx2 >> 4, cp = idx2 & 15;
    const float2 v = *(const float2*)(g0 + (long)row * stride_e + kt + cp * 2);
    *(unsigned*)(lds + row * 64 + cp * 4) = pkbf(v.x, v.y);
  }
}

// 128x128 tile GEMM: C = A[128,K] * Bt[128,K]^T, bf16 MFMA 16x16x32,
// 4 waves in 2x2 quadrants, 4x4 fragments each.
template <bool A_F32>
__device__ __forceinline__ void gemm_core(const char* A0, long as_bytes,
                                          const float* Af, int as_elems,
                                          const char* B0, long bs, int K,
                                          char* As, char* Bs, f32x4 acc[4][4],
                                          int tid) {
  const int l = tid & 63, lane15 = l & 15, quad = l >> 4, wv = tid >> 6;
  const int mw = (wv >> 1) * 64, nw = (wv & 1) * 64;
  for (int kt = 0; kt < K; kt += 32) {
    if (A_F32)
      stage_f32(Af, as_elems, kt, As, tid);
    else
      stage_tile(A0 + (long)kt * 2, as_bytes, As, tid);
    stage_tile(B0 + (long)kt * 2, bs, Bs, tid);
    __syncthreads();
    short8 af[4], bf[4];
#pragma unroll
    for (int i = 0; i < 4; ++i) {
      af[i] = *(const short8*)(As + (mw + i * 16 + lane15) * 64 + quad * 16);
      bf[i] = *(const short8*)(Bs + (nw + i * 16 + lane15) * 64 + quad * 16);
    }
#pragma unroll
    for (int mi = 0; mi < 4; ++mi)
#pragma unroll
      for (int ni = 0; ni < 4; ++ni)
        acc[mi][ni] = __builtin_amdgcn_mfma_f32_16x16x32_bf16(
            af[mi], bf[ni], acc[mi][ni], 0, 0, 0);
    __syncthreads();
  }
}

__device__ __forceinline__ void zero_acc(f32x4 acc[4][4]) {
#pragma unroll
  for (int i = 0; i < 4; ++i)
#pragma unroll
    for (int j = 0; j < 4; ++j) acc[i][j] = (f32x4){0.f, 0.f, 0.f, 0.f};
}

// --------------------------- z = 0, cnt = 0 ---------------------------------
__global__ __launch_bounds__(256) void k_zero2(float4* z, int* cnt) {
  const int b = blockIdx.x;
  if (b < 6144)
    z[b * 256 + threadIdx.x] = (float4){0.f, 0.f, 0.f, 0.f};
  else
    cnt[(b - 6144) * 256 + threadIdx.x] = 0;
}

// ----------------------------- sort kernels ---------------------------------
__global__ __launch_bounds__(256) void k_hist(const int* r0, const int* r1,
                                              const int* r2, int* cnt) {
  const int t = blockIdx.z;
  const int* rcv = t == 0 ? r0 : (t == 1 ? r1 : r2);
  const int e = blockIdx.x * 256 + threadIdx.x;
  atomicAdd(&cnt[t * N_ELEC + rcv[e]], 1);
}

__global__ __launch_bounds__(256) void k_scan(const int* cnt, int* rowptr,
                                              int* cursor) {
  const int t = blockIdx.x, tid = threadIdx.x;
  __shared__ int part[256];
  const int* c = cnt + t * N_ELEC;
  int s = 0;
#pragma unroll
  for (int i = 0; i < 32; ++i) s += c[tid * 32 + i];
  part[tid] = s;
  __syncthreads();
  for (int off = 1; off < 256; off <<= 1) {
    int v = (tid >= off) ? part[tid - off] : 0;
    __syncthreads();
    part[tid] += v;
    __syncthreads();
  }
  int run = (tid == 0) ? 0 : part[tid - 1];
  int* rp = rowptr + t * RPS;
  int* cu = cursor + t * N_ELEC;
  for (int i = 0; i < 32; ++i) {
    rp[tid * 32 + i] = run;
    cu[tid * 32 + i] = run;
    run += c[tid * 32 + i];
  }
  if (tid == 255) rp[N_ELEC] = run;  // = NEDGE
}

__global__ __launch_bounds__(256) void k_place(const int* r0, const int* r1,
                                               const int* r2, const int* s0,
                                               const int* s1, const int* s2,
                                               int* cursor, int* perm,
                                               int* snd_s, int* rcv_s) {
  const int t = blockIdx.z;
  const int* rcv = t == 0 ? r0 : (t == 1 ? r1 : r2);
  const int* snd = t == 0 ? s0 : (t == 1 ? s1 : s2);
  const int e = blockIdx.x * 256 + threadIdx.x;
  const int rr = rcv[e];
  const int pos = atomicAdd(&cursor[t * N_ELEC + rr], 1);
  perm[t * NEDGE + pos] = e;
  snd_s[t * NEDGE + pos] = snd[e];
  rcv_s[t * NEDGE + pos] = rr;
}

// ------------------ prep: f32 weights -> transposed bf16 --------------------
// hwT [KER][EMB], w1T [3][MID][DF], w2T [3][KER][MID], gT [EMB][3*KER]
__global__ __launch_bounds__(256) void k_prep(
    const float* h_w, const float* w1s, const float* w1a, const float* w1n,
    const float* w2s, const float* w2a, const float* w2n, const float* gs,
    const float* ga, const float* gn, u16* hwT, u16* w1T, u16* w2T, u16* gT) {
  int i = blockIdx.x * 256 + threadIdx.x;
  if (i < 65536) {
    int n = i >> 8, k = i & 255;
    hwT[i] = f2bf(h_w[k * 256 + n]);
    return;
  }
  int j = i - 65536;
  if (j < 24576) {
    int t = j >> 13, jj = j & 8191, n = jj >> 6, k = jj & 63;
    const float* w1 = t == 0 ? w1s : (t == 1 ? w1a : w1n);
    w1T[j] = f2bf(w1[k * 128 + n]);
    return;
  }
  j -= 24576;
  if (j < 98304) {
    int t = j >> 15, jj = j & 32767, n = jj >> 7, k = jj & 127;
    const float* w2 = t == 0 ? w2s : (t == 1 ? w2a : w2n);
    w2T[j] = f2bf(w2[k * 256 + n]);
    return;
  }
  j -= 98304;
  if (j < 196608) {
    int n = j / 768, q = j % 768, t = q >> 8, k = q & 255;
    const float* g = t == 0 ? gs : (t == 1 ? ga : gn);
    gT[j] = f2bf(g[k * 256 + n]);
  }
}

// --------------------------- he = electrons @ h_w ---------------------------
__global__ __launch_bounds__(256) void k_he(const float* elec, const u16* hwT,
                                            u16* he) {
  __shared__ char As[8192], Bs[8192];
  f32x4 acc[4][4];
  zero_acc(acc);
  const int m0 = blockIdx.x * 128, n0 = blockIdx.y * 128;
  gemm_core<true>(nullptr, 0, elec + (long)m0 * 256, 256,
                  (const char*)hwT + (long)n0 * 512, 512, 256, As, Bs, acc,
                  threadIdx.x);
  const int l = threadIdx.x & 63, lane15 = l & 15, quad = l >> 4,
            wv = threadIdx.x >> 6;
  const int mw = (wv >> 1) * 64, nw = (wv & 1) * 64;
#pragma unroll
  for (int mi = 0; mi < 4; ++mi)
#pragma unroll
    for (int r = 0; r < 4; ++r) {
      const int row = m0 + mw + mi * 16 + quad * 4 + r;
#pragma unroll
      for (int ni = 0; ni < 4; ++ni) {
        const int col = n0 + nw + ni * 16 + lane15;
        he[row * 256 + col] = f2bf(acc[mi][ni][r]);
      }
    }
}

// ---- fully fused edge kernel -----------------------------------------------
// Per 128-edge tile (receiver-sorted):
//   mid = SSP(bf16(dist[perm]) @ w1 + b1)          (LDS, [128][128] bf16)
//   for n0 in {0,128}:
//     we  = mid @ w2[:,n0:n0+128]                  (MFMA, A from LDS mid)
//     weh = we * src[snd]  (he bf16 / nuc f32)     (in-place in LDS He tile)
//     segmented reduce over receiver runs -> f32 atomics into z
__global__ __launch_bounds__(256) void k_edge(
    const float* d0, const float* d1, const float* d2, const float* b0,
    const float* b1p, const float* b2, const u16* w1T, const u16* w2T,
    const u16* he, const float* nucf, const int* perm, const int* snd_s,
    const int* rcv_s, float* z) {
  __shared__ char mid[128 * CSTR];   // 34816 B
  __shared__ char buf[128 * CSTR];   // dist halves (2x8KB), later He tile
  __shared__ int snd_l[128], rcv_l[128];

  const int t = blockIdx.z;
  const int m0 = blockIdx.x * 128;
  const int tid = threadIdx.x;
  const float* dist = t == 0 ? d0 : (t == 1 ? d1 : d2);
  const float* bias = t == 0 ? b0 : (t == 1 ? b1p : b2);
  const u16* w1t = w1T + t * 8192;    // [128][64]
  const u16* w2t = w2T + t * 32768;   // [256][128]
  const bool is_nuc = (t == 2);

  // tile meta (visible after first barrier)
  if (tid < 128)
    snd_l[tid] = snd_s[t * NEDGE + m0 + tid];
  else
    rcv_l[tid - 128] = rcv_s[t * NEDGE + m0 + tid - 128];

  // stage gathered dist rows as two K-halves [128][32] bf16 (64 B rows)
  int rows[4];
  const int* pm = perm + t * NEDGE + m0;
#pragma unroll
  for (int s = 0; s < 4; ++s) rows[s] = pm[(s * 256 + tid) >> 3];
#pragma unroll
  for (int j = 0; j < 2; ++j)
#pragma unroll
    for (int s = 0; s < 4; ++s) {
      const int idx = s * 256 + tid, row = idx >> 3, ch = idx & 7;
      const float4 v =
          *(const float4*)(dist + (long)rows[s] * 64 + j * 32 + ch * 4);
      uint2 p;
      p.x = pkbf(v.x, v.y);
      p.y = pkbf(v.z, v.w);
      *(uint2*)(buf + j * 8192 + row * 64 + ch * 8) = p;
    }
  __syncthreads();

  const int l = tid & 63, lane15 = l & 15, quad = l >> 4, wv = tid >> 6;
  const int mw = (wv >> 1) * 64, nw = (wv & 1) * 64;

  // GEMM1: [128,64] @ [64,128] -> acc
  f32x4 acc[4][4];
  zero_acc(acc);
#pragma unroll
  for (int j = 0; j < 2; ++j) {
    short8 af[4], bf[4];
#pragma unroll
    for (int i = 0; i < 4; ++i) {
      af[i] = *(const short8*)(buf + j * 8192 + (mw + i * 16 + lane15) * 64 +
                               quad * 16);
      bf[i] = *(const short8*)(w1t + (nw + i * 16 + lane15) * 64 + j * 32 +
                               quad * 8);
    }
#pragma unroll
    for (int mi = 0; mi < 4; ++mi)
#pragma unroll
      for (int ni = 0; ni < 4; ++ni)
        acc[mi][ni] = __builtin_amdgcn_mfma_f32_16x16x32_bf16(
            af[mi], bf[ni], acc[mi][ni], 0, 0, 0);
  }
  __syncthreads();  // done reading dist halves (buf about to be reused)

  // bias + SSP -> mid (bf16, 272 B rows: GEMM2 ds_read_b128 lands 2-way)
#pragma unroll
  for (int mi = 0; mi < 4; ++mi)
#pragma unroll
    for (int r = 0; r < 4; ++r) {
      const int row = mw + mi * 16 + quad * 4 + r;
#pragma unroll
      for (int ni = 0; ni < 4; ++ni) {
        const int col = nw + ni * 16 + lane15;
        const float x = acc[mi][ni][r] + bias[col];
        *(u16*)(mid + row * CSTR + col * 2) = f2bf(ssp_fast(x));
      }
    }
  __syncthreads();  // mid visible to all waves

  u16* HeC = (u16*)buf;
  for (int n0 = 0; n0 < 256; n0 += 128) {
    // GEMM2: A = mid (LDS), B = w2t cols n0.. (direct from global, L2-hot)
    zero_acc(acc);
#pragma unroll
    for (int kt = 0; kt < 128; kt += 32) {
      short8 af[4], bf[4];
#pragma unroll
      for (int i = 0; i < 4; ++i) {
        af[i] = *(const short8*)(mid + (mw + i * 16 + lane15) * CSTR + kt * 2 +
                                 quad * 16);
        bf[i] = *(const short8*)(w2t + (n0 + nw + i * 16 + lane15) * 128 + kt +
                                 quad * 8);
      }
#pragma unroll
      for (int mi = 0; mi < 4; ++mi)
#pragma unroll
        for (int ni = 0; ni < 4; ++ni)
          acc[mi][ni] = __builtin_amdgcn_mfma_f32_16x16x32_bf16(
              af[mi], bf[ni], acc[mi][ni], 0, 0, 0);
    }

    // stage 128 src rows (cols n0..n0+128) into HeC (coalesced 16 B chunks)
    if (!is_nuc) {
#pragma unroll
      for (int c = 0; c < 8; ++c) {
        const int chunk = c * 256 + tid;  // 2048 x 16 B
        const int row = chunk >> 4, off = chunk & 15;
        const uint4 v = *(const uint4*)((const char*)he +
                                        (size_t)snd_l[row] * 512 + n0 * 2 +
                                        off * 16);
        *(uint4*)((char*)HeC + row * CSTR + off * 16) = v;
      }
    } else {
#pragma unroll
      for (int c = 0; c < 8; ++c) {
        const int chunk = c * 256 + tid;
        const int row = chunk >> 4, off = chunk & 15;
        const char* src =
            (const char*)nucf + (size_t)snd_l[row] * 1024 + n0 * 4 + off * 32;
        const float4 a = *(const float4*)src;
        const float4 b = *(const float4*)(src + 16);
        uint4 p;
        p.x = pkbf(a.x, a.y);
        p.y = pkbf(a.z, a.w);
        p.z = pkbf(b.x, b.y);
        p.w = pkbf(b.z, b.w);
        *(uint4*)((char*)HeC + row * CSTR + off * 16) = p;
      }
    }
    __syncthreads();

    // in-place multiply (each cell owned by exactly one lane)
#pragma unroll
    for (int mi = 0; mi < 4; ++mi)
#pragma unroll
      for (int r = 0; r < 4; ++r) {
        const int row = mw + mi * 16 + quad * 4 + r;
#pragma unroll
        for (int ni = 0; ni < 4; ++ni) {
          const int col = nw + ni * 16 + lane15;
          u16* p = (u16*)((char*)HeC + row * CSTR) + col;
          *p = f2bf(acc[mi][ni][r] * bf2f(*p));
        }
      }
    __syncthreads();

    // segmented reduce: wave wv owns rows [wv*32, wv*32+32), lane owns col
    // pair; strip edges forced as segment boundaries (extra atomics only).
    {
      const int cp = l;
      const int rbeg = wv * 32, rend = rbeg + 32;
      float a0 = 0.f, a1 = 0.f;
      int cur = rcv_l[rbeg];
      for (int row = rbeg; row < rend; ++row) {
        const unsigned p = *(const unsigned*)((char*)HeC + row * CSTR + cp * 4);
        a0 += __uint_as_float(p << 16);
        a1 += __uint_as_float(p & 0xffff0000u);
        const int nxt = (row + 1 < rend) ? rcv_l[row + 1] : -1;
        if (nxt != cur) {
          float* zp = z + (size_t)cur * 768 + t * 256 + n0 + cp * 2;
          unsafeAtomicAdd(zp, a0);
          unsafeAtomicAdd(zp + 1, a1);
          a0 = a1 = 0.f;
          cur = nxt;
        }
      }
    }
    __syncthreads();  // HeC reused next n0
  }
}

// ---------- out = electrons_f32 + bf16(z)[8192,768] @ gT^T  (f32) -----------
__global__ __launch_bounds__(256) void k_final(const float* z, const u16* gT,
                                               const float* elec, float* out) {
  __shared__ char As[8192], Bs[8192];
  f32x4 acc[4][4];
  zero_acc(acc);
  const int m0 = blockIdx.x * 128, n0 = blockIdx.y * 128;
  gemm_core<true>(nullptr, 0, z + (long)m0 * 768, 768,
                  (const char*)gT + (long)n0 * 1536, 1536, 768, As, Bs, acc,
                  threadIdx.x);
  const int l = threadIdx.x & 63, lane15 = l & 15, quad = l >> 4,
            wv = threadIdx.x >> 6;
  const int mw = (wv >> 1) * 64, nw = (wv & 1) * 64;
#pragma unroll
  for (int mi = 0; mi < 4; ++mi)
#pragma unroll
    for (int r = 0; r < 4; ++r) {
      const int row = m0 + mw + mi * 16 + quad * 4 + r;
#pragma unroll
      for (int ni = 0; ni < 4; ++ni) {
        const int col = n0 + nw + ni * 16 + lane15;
        out[row * 256 + col] = acc[mi][ni][r] + elec[row * 256 + col];
      }
    }
}

// ---------------------------------------------------------------------------
extern "C" void kernel_launch(void* const* d_in, const int* in_sizes, int n_in,
                              void* d_out, int out_size, void* d_ws,
                              size_t ws_size, hipStream_t stream) {
  int I_dist[3], I_w1[3], I_b1[3], I_w2[3], I_g[3], I_hw;
  if (in_sizes[3] == 64 * 128) {  // setup_inputs() dict order
    for (int t = 0; t < 3; ++t) {
      I_dist[t] = 2 + t * 5 + 0;
      I_w1[t] = 2 + t * 5 + 1;
      I_b1[t] = 2 + t * 5 + 2;
      I_w2[t] = 2 + t * 5 + 3;
      I_g[t] = 2 + t * 5 + 4;
    }
    I_hw = 17;
  } else {  // reference signature order
    I_dist[0] = 2; I_dist[1] = 3; I_dist[2] = 4;
    I_w1[0] = 5;  I_b1[0] = 6;  I_w2[0] = 7;
    I_w1[1] = 8;  I_b1[1] = 9;  I_w2[1] = 10;
    I_w1[2] = 11; I_b1[2] = 12; I_w2[2] = 13;
    I_g[0] = 14; I_g[1] = 15; I_g[2] = 16;
    I_hw = 17;
  }
  const int I_snd[3] = {18, 19, 20};
  const int I_rcv[3] = {21, 22, 23};

  char* ws = (char*)d_ws;
  // workspace layout (bytes). Total ~36 MB.
  u16* he = (u16*)(ws + 0);              //   4,194,304
  u16* hwT = (u16*)(ws + 4194304);       //     131,072
  u16* w1T = (u16*)(ws + 4325376);       //      49,152
  u16* w2T = (u16*)(ws + 4374528);       //     196,608
  u16* gT = (u16*)(ws + 4571136);        //     393,216
  float* z = (float*)(ws + 4964352);     //  25,165,824
  int* cnt = (int*)(ws + 30130176);      //      98,304
  int* rowptr = (int*)(ws + 30228480);   //      99,072
  int* cursor = (int*)(ws + 30327552);   //      98,304
  int* perm = (int*)(ws + 30425856);     //   1,572,864
  int* snd_s = (int*)(ws + 31998720);    //   1,572,864
  int* rcv_s = (int*)(ws + 33571584);    //   1,572,864

  const float* elec = (const float*)d_in[0];
  const float* nuc = (const float*)d_in[1];
  const int* s0 = (const int*)d_in[I_snd[0]];
  const int* s1 = (const int*)d_in[I_snd[1]];
  const int* s2 = (const int*)d_in[I_snd[2]];
  const int* r0 = (const int*)d_in[I_rcv[0]];
  const int* r1 = (const int*)d_in[I_rcv[1]];
  const int* r2 = (const int*)d_in[I_rcv[2]];

  // z = 0 (6144 blocks) + cnt = 0 (96 blocks)
  k_zero2<<<6240, 256, 0, stream>>>((float4*)z, cnt);

  // counting sort by receiver, per type
  k_hist<<<dim3(NEDGE / 256, 1, 3), 256, 0, stream>>>(r0, r1, r2, cnt);
  k_scan<<<3, 256, 0, stream>>>(cnt, rowptr, cursor);
  k_place<<<dim3(NEDGE / 256, 1, 3), 256, 0, stream>>>(r0, r1, r2, s0, s1, s2,
                                                       cursor, perm, snd_s,
                                                       rcv_s);

  k_prep<<<1504, 256, 0, stream>>>(
      (const float*)d_in[I_hw], (const float*)d_in[I_w1[0]],
      (const float*)d_in[I_w1[1]], (const float*)d_in[I_w1[2]],
      (const float*)d_in[I_w2[0]], (const float*)d_in[I_w2[1]],
      (const float*)d_in[I_w2[2]], (const float*)d_in[I_g[0]],
      (const float*)d_in[I_g[1]], (const float*)d_in[I_g[2]], hwT, w1T, w2T,
      gT);

  k_he<<<dim3(N_ELEC / 128, 2), 256, 0, stream>>>(elec, hwT, he);

  k_edge<<<dim3(NEDGE / 128, 1, 3), 256, 0, stream>>>(
      (const float*)d_in[I_dist[0]], (const float*)d_in[I_dist[1]],
      (const float*)d_in[I_dist[2]], (const float*)d_in[I_b1[0]],
      (const float*)d_in[I_b1[1]], (const float*)d_in[I_b1[2]], w1T, w2T, he,
      nuc, perm, snd_s, rcv_s, z);

  k_final<<<dim3(N_ELEC / 128, 2), 256, 0, stream>>>(z, gT, elec,
                                                     (float*)d_out);
}